// Round 20
// baseline (109.448 us; speedup 1.0000x reference)
//
#include <hip/hip_runtime.h>
#include <hip/hip_bf16.h>

#define N_HEADS 16
#define HEAD 64
#define B_SZ 2
#define T_SZ 2048
#define KD 1024
#define M_TOT (B_SZ * T_SZ)   // 4096

typedef short bf16x8 __attribute__((ext_vector_type(8)));
typedef short bf16x4 __attribute__((ext_vector_type(4)));
typedef float f32x4  __attribute__((ext_vector_type(4)));

#define MFMA32(a, b, c) __builtin_amdgcn_mfma_f32_16x16x32_bf16((a), (b), (c), 0, 0, 0)

__device__ __forceinline__ ushort f2bf(float f) {
    __hip_bfloat16 h = __float2bfloat16(f);
    return *reinterpret_cast<ushort*>(&h);
}

// fast bf16 round (round-half-up) for positive finite values: 2 VALU ops
__device__ __forceinline__ ushort f2bf_fast(float f) {
    return (ushort)((__float_as_uint(f) + 0x8000u) >> 16);
}

__device__ __forceinline__ float exp2fast(float x) {
#if __has_builtin(__builtin_amdgcn_exp2f)
    return __builtin_amdgcn_exp2f(x);
#else
    return exp2f(x);
#endif
}

__device__ __forceinline__ void gl2lds16(const ushort* g, void* l) {
    __builtin_amdgcn_global_load_lds(
        (const __attribute__((address_space(1))) unsigned int*)g,
        (__attribute__((address_space(3))) unsigned int*)l, 16, 0, 0);
}

#define RAW_BARRIER() do { asm volatile("" ::: "memory"); \
                           __builtin_amdgcn_s_barrier();  \
                           asm volatile("" ::: "memory"); } while (0)

// ---------------- fused fp32 -> bf16 convert (x + all 4 weights) ----------------
__global__ void cvt_all(const float* __restrict__ x,
                        const float* __restrict__ Wq, const float* __restrict__ Wk,
                        const float* __restrict__ Wv, const float* __restrict__ Wo,
                        ushort* __restrict__ xb, ushort* __restrict__ wb) {
    const int NX = (M_TOT * KD) / 4;
    const int NW = (KD * KD) / 4;
    int i = blockIdx.x * blockDim.x + threadIdx.x;
    float4 v;
    ushort* dst;
    if (i < NX) {
        v = reinterpret_cast<const float4*>(x)[i];
        dst = xb + (size_t)i * 4;
    } else {
        int j = i - NX;
        int w = j >> 18;
        int r = j & (NW - 1);
        const float* s = (w == 0) ? Wq : (w == 1) ? Wk : (w == 2) ? Wv : Wo;
        v = reinterpret_cast<const float4*>(s)[r];
        dst = wb + (size_t)w * KD * KD + (size_t)r * 4;
    }
    ushort4 o;
    o.x = f2bf(v.x); o.y = f2bf(v.y); o.z = f2bf(v.z); o.w = f2bf(v.w);
    *reinterpret_cast<ushort4*>(dst) = o;
}

// ------------- QKV GEMM: single-buffer m97 loop, XCD-chunked swizzle -------------
// 1D grid 768 = 8 XCDs x 96; L = (bid&7)*96 + bid>>3; bm = L&31 (fastest) so the
// 32 consecutive L in an XCD chunk share one B-weight-panel -> stays in that L2.
// V^T stored with PERMUTED t-blocks (b -> b<4?2b:2b-7 within 32-t group) via a
// per-wave LDS [d][t] transpose -> 16B coalesced stores (8 lanes per d-row).
__global__ __launch_bounds__(256) void gemm_qkv(const ushort* __restrict__ A,
                                                const ushort* __restrict__ Bm,
                                                ushort* __restrict__ Qbase) {
    const int bid = blockIdx.x;
    const int L = (bid & 7) * 96 + (bid >> 3);
    const int bm = L & 31;
    const int bn = L >> 5;
    __shared__ alignas(128) char As[16384];   // [128 rows][128B] swizzled bf16
    __shared__ alignas(128) char Bs[16384];
    const int tid = threadIdx.x;
    const int lane = tid & 63;
    const int w = tid >> 6;
    const int wr = w >> 1, wc = w & 1;
    const int r15 = lane & 15, q4 = lane >> 4;
    const int sl8 = lane >> 3;
    const int scol = (((lane & 7) * 16) ^ (sl8 << 4)) >> 1;

    f32x4 acc[4][4] = {};

    for (int k0 = 0; k0 < 1024; k0 += 64) {
        #pragma unroll
        for (int rr = 0; rr < 4; ++rr) {
            int r = rr * 32 + w * 8 + sl8;
            gl2lds16(A  + (size_t)(bm * 128 + r) * 1024 + k0 + scol, &As[(rr * 32 + w * 8) * 128]);
            gl2lds16(Bm + (size_t)(bn * 128 + r) * 1024 + k0 + scol, &Bs[(rr * 32 + w * 8) * 128]);
        }
        asm volatile("s_waitcnt vmcnt(0)" ::: "memory");
        RAW_BARRIER();

        #pragma unroll
        for (int kk = 0; kk < 2; ++kk) {
            bf16x8 af[4], bfr[4];
            #pragma unroll
            for (int m = 0; m < 4; ++m) {
                int row = wr * 64 + m * 16 + r15;
                af[m] = *(const bf16x8*)(&As[row * 128 + ((kk * 64 + q4 * 16) ^ ((row & 7) << 4))]);
            }
            #pragma unroll
            for (int n = 0; n < 4; ++n) {
                int row = wc * 64 + n * 16 + r15;
                bfr[n] = *(const bf16x8*)(&Bs[row * 128 + ((kk * 64 + q4 * 16) ^ ((row & 7) << 4))]);
            }
            #pragma unroll
            for (int m = 0; m < 4; ++m)
                #pragma unroll
                for (int n = 0; n < 4; ++n)
                    acc[m][n] = MFMA32(af[m], bfr[n], acc[m][n]);
        }
        RAW_BARRIER();
    }
    // loop fully drained each iter: no pending loads; LDS free for epilogue scratch

    const size_t seg = (size_t)32 * 2048 * 64;
    const int which = bn >> 3;
    const int row0 = bm * 128 + wr * 64;
    const int col0w = bn * 128 + wc * 64;
    char* ep = ((w & 2) ? Bs : As) + (w & 1) * 8192;   // wave-private 8KB

    if (which == 2) {
        // V: transpose to [d][t] in LDS (permuted t-blocks), then coalesced stores
        #pragma unroll
        for (int m = 0; m < 4; ++m)
            #pragma unroll
            for (int n = 0; n < 4; ++n)
                #pragma unroll
                for (int i = 0; i < 4; ++i) {
                    int dl = n * 16 + r15;                 // d-local 0..63
                    int trow = m * 16 + q4 * 4 + i;        // t-local 0..63
                    int blk = (trow >> 2) & 7;
                    int npos = (blk < 4) ? (blk << 1) : ((blk << 1) - 7);
                    int tcol = (trow & 32) | (npos << 2) | (trow & 3);
                    *(ushort*)(ep + dl * 128 + ((tcol * 2) ^ ((dl & 7) << 4))) =
                        f2bf(acc[m][n][i]);
                }
        const int head = (col0w & 1023) >> 6;              // wave-uniform
        const int bidx = row0 >> 11;
        const int t0 = row0 & 2047;
        #pragma unroll
        for (int j = 0; j < 8; ++j) {
            int d = (lane >> 3) + j * 8;
            int c = lane & 7;
            bf16x8 vv = *(const bf16x8*)(ep + d * 128 + ((c * 16) ^ ((d & 7) << 4)));
            *(bf16x8*)(&Qbase[2 * seg + ((size_t)(bidx * 16 + head) * 64 + d) * 2048 +
                              t0 + c * 8]) = vv;
        }
    } else {
        // Q/K: transpose to [t][d] in LDS, coalesced bf16x8 row stores
        const float sc = (which == 0) ? 0.045084439f : 1.0f;  // (1/sqrt(1024))*log2e
        #pragma unroll
        for (int m = 0; m < 4; ++m)
            #pragma unroll
            for (int n = 0; n < 4; ++n)
                #pragma unroll
                for (int i = 0; i < 4; ++i) {
                    int row = m * 16 + q4 * 4 + i;
                    int dby = (n * 16 + r15) * 2;
                    *(ushort*)(ep + row * 128 + (dby ^ ((row & 7) << 4))) =
                        f2bf(acc[m][n][i] * sc);
                }
        const int head = (col0w & 1023) >> 6;
        #pragma unroll
        for (int j = 0; j < 8; ++j) {
            int row = (lane >> 3) + j * 8;
            bf16x8 vv = *(const bf16x8*)(ep + row * 128 +
                                         (((lane & 7) * 16) ^ ((row & 7) << 4)));
            int grow = row0 + row;
            int bidx = grow >> 11;
            int t = grow & 2047;
            *(bf16x8*)(&Qbase[(size_t)which * seg +
                              (((size_t)(bidx * 16 + head) * 2048 + t) * 64) + (lane & 7) * 8]) = vv;
        }
    }
}

// ---------------- O-projection GEMM: single-buffer, XCD-chunked swizzle ----------
__global__ __launch_bounds__(256) void gemm_o(const ushort* __restrict__ A,
                                              const ushort* __restrict__ Bm,
                                              float* __restrict__ C) {
    const int bid = blockIdx.x;
    const int L = (bid & 7) * 64 + (bid >> 3);   // 512 = 8 x 64, bijective
    const int bm = L & 31;
    const int bn = L >> 5;                        // 0..15
    __shared__ alignas(128) char As[16384];
    __shared__ alignas(128) char Bs[8192];
    const int tid = threadIdx.x;
    const int lane = tid & 63;
    const int w = tid >> 6;
    const int wr = w >> 1, wc = w & 1;
    const int r15 = lane & 15, q4 = lane >> 4;
    const int sl8 = lane >> 3;
    const int scol = (((lane & 7) * 16) ^ (sl8 << 4)) >> 1;

    f32x4 acc[4][2] = {};

    for (int k0 = 0; k0 < 1024; k0 += 64) {
        #pragma unroll
        for (int rr = 0; rr < 4; ++rr) {
            int r = w * 32 + rr * 8 + sl8;
            gl2lds16(A + (size_t)(bm * 128 + r) * 1024 + k0 + scol, &As[(w * 32 + rr * 8) * 128]);
        }
        #pragma unroll
        for (int rr = 0; rr < 2; ++rr) {
            int r = w * 16 + rr * 8 + sl8;
            gl2lds16(Bm + (size_t)(bn * 64 + r) * 1024 + k0 + scol, &Bs[(w * 16 + rr * 8) * 128]);
        }
        asm volatile("s_waitcnt vmcnt(0)" ::: "memory");
        RAW_BARRIER();

        #pragma unroll
        for (int kk = 0; kk < 2; ++kk) {
            bf16x8 af[4], bfr[2];
            #pragma unroll
            for (int m = 0; m < 4; ++m) {
                int row = wr * 64 + m * 16 + r15;
                af[m] = *(const bf16x8*)(&As[row * 128 + ((kk * 64 + q4 * 16) ^ ((row & 7) << 4))]);
            }
            #pragma unroll
            for (int n = 0; n < 2; ++n) {
                int row = wc * 32 + n * 16 + r15;
                bfr[n] = *(const bf16x8*)(&Bs[row * 128 + ((kk * 64 + q4 * 16) ^ ((row & 7) << 4))]);
            }
            #pragma unroll
            for (int m = 0; m < 4; ++m)
                #pragma unroll
                for (int n = 0; n < 2; ++n)
                    acc[m][n] = MFMA32(af[m], bfr[n], acc[m][n]);
        }
        RAW_BARRIER();
    }

    const int row0 = bm * 128 + wr * 64;
    const int col0 = bn * 64 + wc * 32;
    #pragma unroll
    for (int m = 0; m < 4; ++m)
        #pragma unroll
        for (int n = 0; n < 2; ++n)
            #pragma unroll
            for (int i = 0; i < 4; ++i)
                C[(size_t)(row0 + m * 16 + q4 * 4 + i) * 1024 + col0 + n * 16 + r15] =
                    acc[m][n][i];
}

// ------- flash attention: kv-split, b128 V reads, MFMA row-sum (FROZEN) ----------
__global__ __launch_bounds__(1024) void attn_fwd(const ushort* __restrict__ Qh,
                                                 const ushort* __restrict__ Kh,
                                                 const ushort* __restrict__ Vt,
                                                 ushort* __restrict__ Ob) {
    const int bh = blockIdx.x;
    const int qt = blockIdx.y;
    const int tid = threadIdx.x;
    const int lane = tid & 63, w = tid >> 6;
    const int grp = w >> 3, wl = w & 7;
    const int r15 = lane & 15, q4 = lane >> 4;

    const ushort* Qp = Qh + (size_t)bh * T_SZ * HEAD;
    const ushort* Kp = Kh + (size_t)bh * T_SZ * HEAD;
    const ushort* Vp = Vt + (size_t)bh * HEAD * T_SZ;

    __shared__ alignas(16) char SMEM[65536];
    char* Kbuf = SMEM + grp * 32768;
    char* Vbuf = Kbuf + 16384;

    const int srow = wl * 8 + (lane >> 3);
    const int sslot = (lane & 7) * 16;
    const int ssb = (sslot ^ ((srow & 7) << 4)) >> 1;
    const int kvbase = grp << 10;

    const int q0 = qt * 256 + wl * 32;
    bf16x8 qf[2][2];
    #pragma unroll
    for (int cc = 0; cc < 2; ++cc) {
        qf[cc][0] = *(const bf16x8*)(&Qp[(size_t)(q0 + cc * 16 + r15) * 64 + q4 * 8]);
        qf[cc][1] = *(const bf16x8*)(&Qp[(size_t)(q0 + cc * 16 + r15) * 64 + 32 + q4 * 8]);
    }

    const bf16x8 ones8 = {0x3F80, 0x3F80, 0x3F80, 0x3F80, 0x3F80, 0x3F80, 0x3F80, 0x3F80};

    f32x4 acc[2][4] = {};
    f32x4 acc_l[2] = {};

    #define STAGE(buf, kv0)                                                      \
        {                                                                        \
            gl2lds16(Kp + (size_t)(kvbase + (kv0) + srow) * 64 + ssb,            \
                     Kbuf + (buf) * 8192 + wl * 8 * 128);                        \
            gl2lds16(Vp + (size_t)srow * 2048 + kvbase + (kv0) + ssb,            \
                     Vbuf + (buf) * 8192 + wl * 8 * 128);                        \
        }

    STAGE(0, 0);
    int cur = 0;
    for (int it = 0; it < 16; ++it) {
        STAGE(cur ^ 1, ((it + 1) & 15) * 64);
        asm volatile("s_waitcnt vmcnt(2)" ::: "memory");
        RAW_BARRIER();

        const char* Ks = Kbuf + cur * 8192;
        const char* Vs = Vbuf + cur * 8192;

        bf16x8 kf[4][2];
        #pragma unroll
        for (int t4 = 0; t4 < 4; ++t4) {
            int row = t4 * 16 + r15;
            int sw = (row & 7) << 4;
            kf[t4][0] = *(const bf16x8*)(&Ks[row * 128 + ((q4 * 16) ^ sw)]);
            kf[t4][1] = *(const bf16x8*)(&Ks[row * 128 + ((64 + q4 * 16) ^ sw)]);
        }
        bf16x8 vf8[2][4];
        #pragma unroll
        for (int dt = 0; dt < 4; ++dt) {
            int row = dt * 16 + r15;
            int sw = (row & 7) << 4;
            #pragma unroll
            for (int t32 = 0; t32 < 2; ++t32)
                vf8[t32][dt] = *(const bf16x8*)(&Vs[row * 128 + ((t32 * 64 + q4 * 16) ^ sw)]);
        }

        f32x4 z[2][4];
        #pragma unroll
        for (int cc = 0; cc < 2; ++cc)
            #pragma unroll
            for (int t4 = 0; t4 < 4; ++t4) {
                f32x4 zz = {};
                zz = MFMA32(kf[t4][0], qf[cc][0], zz);
                zz = MFMA32(kf[t4][1], qf[cc][1], zz);
                z[cc][t4] = zz;
            }

        bf16x8 pb8[2][2];
        #pragma unroll
        for (int cc = 0; cc < 2; ++cc)
            #pragma unroll
            for (int t32 = 0; t32 < 2; ++t32)
                #pragma unroll
                for (int i = 0; i < 4; ++i) {
                    pb8[cc][t32][i]     = (short)f2bf_fast(exp2fast(z[cc][2 * t32][i]));
                    pb8[cc][t32][4 + i] = (short)f2bf_fast(exp2fast(z[cc][2 * t32 + 1][i]));
                }

        #pragma unroll
        for (int t32 = 0; t32 < 2; ++t32) {
            #pragma unroll
            for (int dt = 0; dt < 4; ++dt)
                #pragma unroll
                for (int cc = 0; cc < 2; ++cc)
                    acc[cc][dt] = MFMA32(vf8[t32][dt], pb8[cc][t32], acc[cc][dt]);
            #pragma unroll
            for (int cc = 0; cc < 2; ++cc)
                acc_l[cc] = MFMA32(ones8, pb8[cc][t32], acc_l[cc]);
        }

        RAW_BARRIER();
        cur ^= 1;
    }
    #undef STAGE

    asm volatile("s_waitcnt vmcnt(0)" ::: "memory");
    __syncthreads();

    float l0 = acc_l[0][0], l1 = acc_l[1][0];
    {
        float* MB = (float*)SMEM;
        #pragma unroll
        for (int rnd = 0; rnd < 2; ++rnd) {
            __syncthreads();
            if (grp == 1 && (wl >> 2) == rnd) {
                float* p = MB + (((wl & 3) * 64 + lane) * 34);
                #pragma unroll
                for (int cc = 0; cc < 2; ++cc)
                    #pragma unroll
                    for (int dt = 0; dt < 4; ++dt) {
                        *(float2*)(p + (cc * 4 + dt) * 4)     = make_float2(acc[cc][dt][0], acc[cc][dt][1]);
                        *(float2*)(p + (cc * 4 + dt) * 4 + 2) = make_float2(acc[cc][dt][2], acc[cc][dt][3]);
                    }
                *(float2*)(p + 32) = make_float2(l0, l1);
            }
            __syncthreads();
            if (grp == 0 && (wl >> 2) == rnd) {
                const float* p = MB + (((wl & 3) * 64 + lane) * 34);
                #pragma unroll
                for (int cc = 0; cc < 2; ++cc)
                    #pragma unroll
                    for (int dt = 0; dt < 4; ++dt)
                        #pragma unroll
                        for (int i = 0; i < 4; ++i)
                            acc[cc][dt][i] += p[(cc * 4 + dt) * 4 + i];
                l0 += p[32];
                l1 += p[33];
            }
        }
    }

    if (grp == 0) {
        const int b = bh >> 4, h = bh & 15;
        #pragma unroll
        for (int cc = 0; cc < 2; ++cc) {
            float inv = 1.0f / (cc ? l1 : l0);
            int q = q0 + cc * 16 + r15;
            #pragma unroll
            for (int dt = 0; dt < 4; ++dt) {
                ushort4 o;
                o.x = f2bf(acc[cc][dt][0] * inv);
                o.y = f2bf(acc[cc][dt][1] * inv);
                o.z = f2bf(acc[cc][dt][2] * inv);
                o.w = f2bf(acc[cc][dt][3] * inv);
                *(ushort4*)(&Ob[((size_t)(b * T_SZ + q)) * KD + h * HEAD + dt * 16 + q4 * 4]) = o;
            }
        }
    }
}

extern "C" void kernel_launch(void* const* d_in, const int* in_sizes, int n_in,
                              void* d_out, int out_size, void* d_ws, size_t ws_size,
                              hipStream_t stream) {
    const float* x  = (const float*)d_in[0];
    const float* Wq = (const float*)d_in[1];
    const float* Wk = (const float*)d_in[2];
    const float* Wv = (const float*)d_in[3];
    const float* Wo = (const float*)d_in[4];

    char* ws = (char*)d_ws;
    const size_t MB = 1024 * 1024;
    ushort* xb    = (ushort*)(ws + 0);
    ushort* Wqkvb = (ushort*)(ws + 8  * MB);
    ushort* Wob   = Wqkvb + 3 * (size_t)KD * KD;
    ushort* Qh    = (ushort*)(ws + 16 * MB);
    ushort* Kh    = (ushort*)(ws + 24 * MB);
    ushort* VhT   = (ushort*)(ws + 32 * MB);
    ushort* Ob    = (ushort*)(ws + 40 * MB);

    {
        int total4 = (M_TOT * KD) / 4 + KD * KD;
        cvt_all<<<total4 / 256, 256, 0, stream>>>(x, Wq, Wk, Wv, Wo, xb, Wqkvb);
    }

    gemm_qkv<<<768, 256, 0, stream>>>(xb, Wqkvb, Qh);
    attn_fwd<<<dim3(32, 8), 1024, 0, stream>>>(Qh, Kh, VhT, Ob);
    gemm_o<<<512, 256, 0, stream>>>(Ob, Wob, (float*)d_out);
}

// Round 21
// 107.331 us; speedup vs baseline: 1.0197x; 1.0197x over previous
//
#include <hip/hip_runtime.h>
#include <hip/hip_bf16.h>

#define N_HEADS 16
#define HEAD 64
#define B_SZ 2
#define T_SZ 2048
#define KD 1024
#define M_TOT (B_SZ * T_SZ)   // 4096

typedef short bf16x8 __attribute__((ext_vector_type(8)));
typedef short bf16x4 __attribute__((ext_vector_type(4)));
typedef float f32x4  __attribute__((ext_vector_type(4)));

#define MFMA32(a, b, c) __builtin_amdgcn_mfma_f32_16x16x32_bf16((a), (b), (c), 0, 0, 0)

__device__ __forceinline__ ushort f2bf(float f) {
    __hip_bfloat16 h = __float2bfloat16(f);
    return *reinterpret_cast<ushort*>(&h);
}

// fast bf16 round (round-half-up) for positive finite values: 2 VALU ops
__device__ __forceinline__ ushort f2bf_fast(float f) {
    return (ushort)((__float_as_uint(f) + 0x8000u) >> 16);
}

__device__ __forceinline__ float exp2fast(float x) {
#if __has_builtin(__builtin_amdgcn_exp2f)
    return __builtin_amdgcn_exp2f(x);
#else
    return exp2f(x);
#endif
}

__device__ __forceinline__ void gl2lds16(const ushort* g, void* l) {
    __builtin_amdgcn_global_load_lds(
        (const __attribute__((address_space(1))) unsigned int*)g,
        (__attribute__((address_space(3))) unsigned int*)l, 16, 0, 0);
}

#define RAW_BARRIER() do { asm volatile("" ::: "memory"); \
                           __builtin_amdgcn_s_barrier();  \
                           asm volatile("" ::: "memory"); } while (0)

// ---------------- fused fp32 -> bf16 convert (x + all 4 weights) ----------------
__global__ void cvt_all(const float* __restrict__ x,
                        const float* __restrict__ Wq, const float* __restrict__ Wk,
                        const float* __restrict__ Wv, const float* __restrict__ Wo,
                        ushort* __restrict__ xb, ushort* __restrict__ wb) {
    const int NX = (M_TOT * KD) / 4;
    const int NW = (KD * KD) / 4;
    int i = blockIdx.x * blockDim.x + threadIdx.x;
    float4 v;
    ushort* dst;
    if (i < NX) {
        v = reinterpret_cast<const float4*>(x)[i];
        dst = xb + (size_t)i * 4;
    } else {
        int j = i - NX;
        int w = j >> 18;
        int r = j & (NW - 1);
        const float* s = (w == 0) ? Wq : (w == 1) ? Wk : (w == 2) ? Wv : Wo;
        v = reinterpret_cast<const float4*>(s)[r];
        dst = wb + (size_t)w * KD * KD + (size_t)r * 4;
    }
    ushort4 o;
    o.x = f2bf(v.x); o.y = f2bf(v.y); o.z = f2bf(v.z); o.w = f2bf(v.w);
    *reinterpret_cast<ushort4*>(dst) = o;
}

// ------------- QKV GEMM: single-buffer m97 loop, 2D grid (bm fastest) ------------
// 2D dispatch: bid%8 = bm%8 = XCD -> each XCD holds 4 A-panels (1MB, L2-resident).
// (r20 lesson: chunking by bn thrashed A's 8MB working set over the 4MB L2.)
// V^T stored with PERMUTED t-blocks (b -> b<4?2b:2b-7 within 32-t group) via a
// per-wave LDS [d][t] transpose -> 16B coalesced stores (8 lanes per d-row).
__global__ __launch_bounds__(256) void gemm_qkv(const ushort* __restrict__ A,
                                                const ushort* __restrict__ Bm,
                                                ushort* __restrict__ Qbase) {
    const int bm = blockIdx.x;
    const int bn = blockIdx.y;
    __shared__ alignas(128) char As[16384];   // [128 rows][128B] swizzled bf16
    __shared__ alignas(128) char Bs[16384];
    const int tid = threadIdx.x;
    const int lane = tid & 63;
    const int w = tid >> 6;
    const int wr = w >> 1, wc = w & 1;
    const int r15 = lane & 15, q4 = lane >> 4;
    const int sl8 = lane >> 3;
    const int scol = (((lane & 7) * 16) ^ (sl8 << 4)) >> 1;

    f32x4 acc[4][4] = {};

    for (int k0 = 0; k0 < 1024; k0 += 64) {
        #pragma unroll
        for (int rr = 0; rr < 4; ++rr) {
            int r = rr * 32 + w * 8 + sl8;
            gl2lds16(A  + (size_t)(bm * 128 + r) * 1024 + k0 + scol, &As[(rr * 32 + w * 8) * 128]);
            gl2lds16(Bm + (size_t)(bn * 128 + r) * 1024 + k0 + scol, &Bs[(rr * 32 + w * 8) * 128]);
        }
        asm volatile("s_waitcnt vmcnt(0)" ::: "memory");
        RAW_BARRIER();

        #pragma unroll
        for (int kk = 0; kk < 2; ++kk) {
            bf16x8 af[4], bfr[4];
            #pragma unroll
            for (int m = 0; m < 4; ++m) {
                int row = wr * 64 + m * 16 + r15;
                af[m] = *(const bf16x8*)(&As[row * 128 + ((kk * 64 + q4 * 16) ^ ((row & 7) << 4))]);
            }
            #pragma unroll
            for (int n = 0; n < 4; ++n) {
                int row = wc * 64 + n * 16 + r15;
                bfr[n] = *(const bf16x8*)(&Bs[row * 128 + ((kk * 64 + q4 * 16) ^ ((row & 7) << 4))]);
            }
            #pragma unroll
            for (int m = 0; m < 4; ++m)
                #pragma unroll
                for (int n = 0; n < 4; ++n)
                    acc[m][n] = MFMA32(af[m], bfr[n], acc[m][n]);
        }
        RAW_BARRIER();
    }
    // loop fully drained each iter: no pending loads; LDS free for epilogue scratch

    const size_t seg = (size_t)32 * 2048 * 64;
    const int which = bn >> 3;
    const int row0 = bm * 128 + wr * 64;
    const int col0w = bn * 128 + wc * 64;
    char* ep = ((w & 2) ? Bs : As) + (w & 1) * 8192;   // wave-private 8KB

    if (which == 2) {
        // V: transpose to [d][t] in LDS (permuted t-blocks), then coalesced stores
        #pragma unroll
        for (int m = 0; m < 4; ++m)
            #pragma unroll
            for (int n = 0; n < 4; ++n)
                #pragma unroll
                for (int i = 0; i < 4; ++i) {
                    int dl = n * 16 + r15;                 // d-local 0..63
                    int trow = m * 16 + q4 * 4 + i;        // t-local 0..63
                    int blk = (trow >> 2) & 7;
                    int npos = (blk < 4) ? (blk << 1) : ((blk << 1) - 7);
                    int tcol = (trow & 32) | (npos << 2) | (trow & 3);
                    *(ushort*)(ep + dl * 128 + ((tcol * 2) ^ ((dl & 7) << 4))) =
                        f2bf(acc[m][n][i]);
                }
        const int head = (col0w & 1023) >> 6;              // wave-uniform
        const int bidx = row0 >> 11;
        const int t0 = row0 & 2047;
        #pragma unroll
        for (int j = 0; j < 8; ++j) {
            int d = (lane >> 3) + j * 8;
            int c = lane & 7;
            bf16x8 vv = *(const bf16x8*)(ep + d * 128 + ((c * 16) ^ ((d & 7) << 4)));
            *(bf16x8*)(&Qbase[2 * seg + ((size_t)(bidx * 16 + head) * 64 + d) * 2048 +
                              t0 + c * 8]) = vv;
        }
    } else {
        // Q/K: transpose to [t][d] in LDS, coalesced bf16x8 row stores
        const float sc = (which == 0) ? 0.045084439f : 1.0f;  // (1/sqrt(1024))*log2e
        #pragma unroll
        for (int m = 0; m < 4; ++m)
            #pragma unroll
            for (int n = 0; n < 4; ++n)
                #pragma unroll
                for (int i = 0; i < 4; ++i) {
                    int row = m * 16 + q4 * 4 + i;
                    int dby = (n * 16 + r15) * 2;
                    *(ushort*)(ep + row * 128 + (dby ^ ((row & 7) << 4))) =
                        f2bf(acc[m][n][i] * sc);
                }
        const int head = (col0w & 1023) >> 6;
        #pragma unroll
        for (int j = 0; j < 8; ++j) {
            int row = (lane >> 3) + j * 8;
            bf16x8 vv = *(const bf16x8*)(ep + row * 128 +
                                         (((lane & 7) * 16) ^ ((row & 7) << 4)));
            int grow = row0 + row;
            int bidx = grow >> 11;
            int t = grow & 2047;
            *(bf16x8*)(&Qbase[(size_t)which * seg +
                              (((size_t)(bidx * 16 + head) * 2048 + t) * 64) + (lane & 7) * 8]) = vv;
        }
    }
}

// ---------------- O-projection GEMM: single-buffer, 2D grid ----------------------
__global__ __launch_bounds__(256) void gemm_o(const ushort* __restrict__ A,
                                              const ushort* __restrict__ Bm,
                                              float* __restrict__ C) {
    const int bm = blockIdx.x;
    const int bn = blockIdx.y;                    // 0..15
    __shared__ alignas(128) char As[16384];
    __shared__ alignas(128) char Bs[8192];
    const int tid = threadIdx.x;
    const int lane = tid & 63;
    const int w = tid >> 6;
    const int wr = w >> 1, wc = w & 1;
    const int r15 = lane & 15, q4 = lane >> 4;
    const int sl8 = lane >> 3;
    const int scol = (((lane & 7) * 16) ^ (sl8 << 4)) >> 1;

    f32x4 acc[4][2] = {};

    for (int k0 = 0; k0 < 1024; k0 += 64) {
        #pragma unroll
        for (int rr = 0; rr < 4; ++rr) {
            int r = w * 32 + rr * 8 + sl8;
            gl2lds16(A + (size_t)(bm * 128 + r) * 1024 + k0 + scol, &As[(w * 32 + rr * 8) * 128]);
        }
        #pragma unroll
        for (int rr = 0; rr < 2; ++rr) {
            int r = w * 16 + rr * 8 + sl8;
            gl2lds16(Bm + (size_t)(bn * 64 + r) * 1024 + k0 + scol, &Bs[(w * 16 + rr * 8) * 128]);
        }
        asm volatile("s_waitcnt vmcnt(0)" ::: "memory");
        RAW_BARRIER();

        #pragma unroll
        for (int kk = 0; kk < 2; ++kk) {
            bf16x8 af[4], bfr[2];
            #pragma unroll
            for (int m = 0; m < 4; ++m) {
                int row = wr * 64 + m * 16 + r15;
                af[m] = *(const bf16x8*)(&As[row * 128 + ((kk * 64 + q4 * 16) ^ ((row & 7) << 4))]);
            }
            #pragma unroll
            for (int n = 0; n < 2; ++n) {
                int row = wc * 32 + n * 16 + r15;
                bfr[n] = *(const bf16x8*)(&Bs[row * 128 + ((kk * 64 + q4 * 16) ^ ((row & 7) << 4))]);
            }
            #pragma unroll
            for (int m = 0; m < 4; ++m)
                #pragma unroll
                for (int n = 0; n < 2; ++n)
                    acc[m][n] = MFMA32(af[m], bfr[n], acc[m][n]);
        }
        RAW_BARRIER();
    }

    const int row0 = bm * 128 + wr * 64;
    const int col0 = bn * 64 + wc * 32;
    #pragma unroll
    for (int m = 0; m < 4; ++m)
        #pragma unroll
        for (int n = 0; n < 2; ++n)
            #pragma unroll
            for (int i = 0; i < 4; ++i)
                C[(size_t)(row0 + m * 16 + q4 * 4 + i) * 1024 + col0 + n * 16 + r15] =
                    acc[m][n][i];
}

// ------- flash attention: kv-split, b128 V reads, MFMA row-sum (FROZEN) ----------
__global__ __launch_bounds__(1024) void attn_fwd(const ushort* __restrict__ Qh,
                                                 const ushort* __restrict__ Kh,
                                                 const ushort* __restrict__ Vt,
                                                 ushort* __restrict__ Ob) {
    const int bh = blockIdx.x;
    const int qt = blockIdx.y;
    const int tid = threadIdx.x;
    const int lane = tid & 63, w = tid >> 6;
    const int grp = w >> 3, wl = w & 7;
    const int r15 = lane & 15, q4 = lane >> 4;

    const ushort* Qp = Qh + (size_t)bh * T_SZ * HEAD;
    const ushort* Kp = Kh + (size_t)bh * T_SZ * HEAD;
    const ushort* Vp = Vt + (size_t)bh * HEAD * T_SZ;

    __shared__ alignas(16) char SMEM[65536];
    char* Kbuf = SMEM + grp * 32768;
    char* Vbuf = Kbuf + 16384;

    const int srow = wl * 8 + (lane >> 3);
    const int sslot = (lane & 7) * 16;
    const int ssb = (sslot ^ ((srow & 7) << 4)) >> 1;
    const int kvbase = grp << 10;

    const int q0 = qt * 256 + wl * 32;
    bf16x8 qf[2][2];
    #pragma unroll
    for (int cc = 0; cc < 2; ++cc) {
        qf[cc][0] = *(const bf16x8*)(&Qp[(size_t)(q0 + cc * 16 + r15) * 64 + q4 * 8]);
        qf[cc][1] = *(const bf16x8*)(&Qp[(size_t)(q0 + cc * 16 + r15) * 64 + 32 + q4 * 8]);
    }

    const bf16x8 ones8 = {0x3F80, 0x3F80, 0x3F80, 0x3F80, 0x3F80, 0x3F80, 0x3F80, 0x3F80};

    f32x4 acc[2][4] = {};
    f32x4 acc_l[2] = {};

    #define STAGE(buf, kv0)                                                      \
        {                                                                        \
            gl2lds16(Kp + (size_t)(kvbase + (kv0) + srow) * 64 + ssb,            \
                     Kbuf + (buf) * 8192 + wl * 8 * 128);                        \
            gl2lds16(Vp + (size_t)srow * 2048 + kvbase + (kv0) + ssb,            \
                     Vbuf + (buf) * 8192 + wl * 8 * 128);                        \
        }

    STAGE(0, 0);
    int cur = 0;
    for (int it = 0; it < 16; ++it) {
        STAGE(cur ^ 1, ((it + 1) & 15) * 64);
        asm volatile("s_waitcnt vmcnt(2)" ::: "memory");
        RAW_BARRIER();

        const char* Ks = Kbuf + cur * 8192;
        const char* Vs = Vbuf + cur * 8192;

        bf16x8 kf[4][2];
        #pragma unroll
        for (int t4 = 0; t4 < 4; ++t4) {
            int row = t4 * 16 + r15;
            int sw = (row & 7) << 4;
            kf[t4][0] = *(const bf16x8*)(&Ks[row * 128 + ((q4 * 16) ^ sw)]);
            kf[t4][1] = *(const bf16x8*)(&Ks[row * 128 + ((64 + q4 * 16) ^ sw)]);
        }
        bf16x8 vf8[2][4];
        #pragma unroll
        for (int dt = 0; dt < 4; ++dt) {
            int row = dt * 16 + r15;
            int sw = (row & 7) << 4;
            #pragma unroll
            for (int t32 = 0; t32 < 2; ++t32)
                vf8[t32][dt] = *(const bf16x8*)(&Vs[row * 128 + ((t32 * 64 + q4 * 16) ^ sw)]);
        }

        f32x4 z[2][4];
        #pragma unroll
        for (int cc = 0; cc < 2; ++cc)
            #pragma unroll
            for (int t4 = 0; t4 < 4; ++t4) {
                f32x4 zz = {};
                zz = MFMA32(kf[t4][0], qf[cc][0], zz);
                zz = MFMA32(kf[t4][1], qf[cc][1], zz);
                z[cc][t4] = zz;
            }

        bf16x8 pb8[2][2];
        #pragma unroll
        for (int cc = 0; cc < 2; ++cc)
            #pragma unroll
            for (int t32 = 0; t32 < 2; ++t32)
                #pragma unroll
                for (int i = 0; i < 4; ++i) {
                    pb8[cc][t32][i]     = (short)f2bf_fast(exp2fast(z[cc][2 * t32][i]));
                    pb8[cc][t32][4 + i] = (short)f2bf_fast(exp2fast(z[cc][2 * t32 + 1][i]));
                }

        #pragma unroll
        for (int t32 = 0; t32 < 2; ++t32) {
            #pragma unroll
            for (int dt = 0; dt < 4; ++dt)
                #pragma unroll
                for (int cc = 0; cc < 2; ++cc)
                    acc[cc][dt] = MFMA32(vf8[t32][dt], pb8[cc][t32], acc[cc][dt]);
            #pragma unroll
            for (int cc = 0; cc < 2; ++cc)
                acc_l[cc] = MFMA32(ones8, pb8[cc][t32], acc_l[cc]);
        }

        RAW_BARRIER();
        cur ^= 1;
    }
    #undef STAGE

    asm volatile("s_waitcnt vmcnt(0)" ::: "memory");
    __syncthreads();

    float l0 = acc_l[0][0], l1 = acc_l[1][0];
    {
        float* MB = (float*)SMEM;
        #pragma unroll
        for (int rnd = 0; rnd < 2; ++rnd) {
            __syncthreads();
            if (grp == 1 && (wl >> 2) == rnd) {
                float* p = MB + (((wl & 3) * 64 + lane) * 34);
                #pragma unroll
                for (int cc = 0; cc < 2; ++cc)
                    #pragma unroll
                    for (int dt = 0; dt < 4; ++dt) {
                        *(float2*)(p + (cc * 4 + dt) * 4)     = make_float2(acc[cc][dt][0], acc[cc][dt][1]);
                        *(float2*)(p + (cc * 4 + dt) * 4 + 2) = make_float2(acc[cc][dt][2], acc[cc][dt][3]);
                    }
                *(float2*)(p + 32) = make_float2(l0, l1);
            }
            __syncthreads();
            if (grp == 0 && (wl >> 2) == rnd) {
                const float* p = MB + (((wl & 3) * 64 + lane) * 34);
                #pragma unroll
                for (int cc = 0; cc < 2; ++cc)
                    #pragma unroll
                    for (int dt = 0; dt < 4; ++dt)
                        #pragma unroll
                        for (int i = 0; i < 4; ++i)
                            acc[cc][dt][i] += p[(cc * 4 + dt) * 4 + i];
                l0 += p[32];
                l1 += p[33];
            }
        }
    }

    if (grp == 0) {
        const int b = bh >> 4, h = bh & 15;
        #pragma unroll
        for (int cc = 0; cc < 2; ++cc) {
            float inv = 1.0f / (cc ? l1 : l0);
            int q = q0 + cc * 16 + r15;
            #pragma unroll
            for (int dt = 0; dt < 4; ++dt) {
                ushort4 o;
                o.x = f2bf(acc[cc][dt][0] * inv);
                o.y = f2bf(acc[cc][dt][1] * inv);
                o.z = f2bf(acc[cc][dt][2] * inv);
                o.w = f2bf(acc[cc][dt][3] * inv);
                *(ushort4*)(&Ob[((size_t)(b * T_SZ + q)) * KD + h * HEAD + dt * 16 + q4 * 4]) = o;
            }
        }
    }
}

extern "C" void kernel_launch(void* const* d_in, const int* in_sizes, int n_in,
                              void* d_out, int out_size, void* d_ws, size_t ws_size,
                              hipStream_t stream) {
    const float* x  = (const float*)d_in[0];
    const float* Wq = (const float*)d_in[1];
    const float* Wk = (const float*)d_in[2];
    const float* Wv = (const float*)d_in[3];
    const float* Wo = (const float*)d_in[4];

    char* ws = (char*)d_ws;
    const size_t MB = 1024 * 1024;
    ushort* xb    = (ushort*)(ws + 0);
    ushort* Wqkvb = (ushort*)(ws + 8  * MB);
    ushort* Wob   = Wqkvb + 3 * (size_t)KD * KD;
    ushort* Qh    = (ushort*)(ws + 16 * MB);
    ushort* Kh    = (ushort*)(ws + 24 * MB);
    ushort* VhT   = (ushort*)(ws + 32 * MB);
    ushort* Ob    = (ushort*)(ws + 40 * MB);

    {
        int total4 = (M_TOT * KD) / 4 + KD * KD;
        cvt_all<<<total4 / 256, 256, 0, stream>>>(x, Wq, Wk, Wv, Wo, xb, Wqkvb);
    }

    gemm_qkv<<<dim3(32, 24), 256, 0, stream>>>(xb, Wqkvb, Qh);
    attn_fwd<<<dim3(32, 8), 1024, 0, stream>>>(Qh, Kh, VhT, Ob);
    gemm_o<<<dim3(32, 16), 256, 0, stream>>>(Ob, Wob, (float*)d_out);
}

// Round 22
// 100.209 us; speedup vs baseline: 1.0922x; 1.0711x over previous
//
#include <hip/hip_runtime.h>
#include <hip/hip_bf16.h>

#define N_HEADS 16
#define HEAD 64
#define B_SZ 2
#define T_SZ 2048
#define KD 1024
#define M_TOT (B_SZ * T_SZ)   // 4096

typedef short bf16x8 __attribute__((ext_vector_type(8)));
typedef short bf16x4 __attribute__((ext_vector_type(4)));
typedef float f32x4  __attribute__((ext_vector_type(4)));

#define MFMA32(a, b, c) __builtin_amdgcn_mfma_f32_16x16x32_bf16((a), (b), (c), 0, 0, 0)

__device__ __forceinline__ ushort f2bf(float f) {
    __hip_bfloat16 h = __float2bfloat16(f);
    return *reinterpret_cast<ushort*>(&h);
}

// fast bf16 round (round-half-up) for positive finite values: 2 VALU ops
__device__ __forceinline__ ushort f2bf_fast(float f) {
    return (ushort)((__float_as_uint(f) + 0x8000u) >> 16);
}

__device__ __forceinline__ float exp2fast(float x) {
#if __has_builtin(__builtin_amdgcn_exp2f)
    return __builtin_amdgcn_exp2f(x);
#else
    return exp2f(x);
#endif
}

__device__ __forceinline__ void gl2lds16(const ushort* g, void* l) {
    __builtin_amdgcn_global_load_lds(
        (const __attribute__((address_space(1))) unsigned int*)g,
        (__attribute__((address_space(3))) unsigned int*)l, 16, 0, 0);
}

#define RAW_BARRIER() do { asm volatile("" ::: "memory"); \
                           __builtin_amdgcn_s_barrier();  \
                           asm volatile("" ::: "memory"); } while (0)

// ---------------- fused fp32 -> bf16 convert (x + all 4 weights) ----------------
__global__ void cvt_all(const float* __restrict__ x,
                        const float* __restrict__ Wq, const float* __restrict__ Wk,
                        const float* __restrict__ Wv, const float* __restrict__ Wo,
                        ushort* __restrict__ xb, ushort* __restrict__ wb) {
    const int NX = (M_TOT * KD) / 4;
    const int NW = (KD * KD) / 4;
    int i = blockIdx.x * blockDim.x + threadIdx.x;
    float4 v;
    ushort* dst;
    if (i < NX) {
        v = reinterpret_cast<const float4*>(x)[i];
        dst = xb + (size_t)i * 4;
    } else {
        int j = i - NX;
        int w = j >> 18;
        int r = j & (NW - 1);
        const float* s = (w == 0) ? Wq : (w == 1) ? Wk : (w == 2) ? Wv : Wo;
        v = reinterpret_cast<const float4*>(s)[r];
        dst = wb + (size_t)w * KD * KD + (size_t)r * 4;
    }
    ushort4 o;
    o.x = f2bf(v.x); o.y = f2bf(v.y); o.z = f2bf(v.z); o.w = f2bf(v.w);
    *reinterpret_cast<ushort4*>(dst) = o;
}

// ------------- QKV GEMM: 8 waves/block (2x4), 128x128 tile, single-buffer --------
// 3 blocks/CU x 8 waves = 24 waves/CU (6/SIMD) -- 2x the latency-hiding pool of
// the 4-wave version (which measured Occupancy 14%, latency-stalled).
// Wave tile 64x32 (wr=w>>2 row-half, wc=w&3 col-quarter), acc[4][2].
// Epilogues: per-wave 4KB LDS transpose scratch (XOR-swizzled), coalesced stores.
// V^T stored with PERMUTED t-blocks (b -> b<4?2b:2b-7 within 32-t group).
__global__ __launch_bounds__(512) void gemm_qkv(const ushort* __restrict__ A,
                                                const ushort* __restrict__ Bm,
                                                ushort* __restrict__ Qbase) {
    const int bm = blockIdx.x;
    const int bn = blockIdx.y;
    __shared__ alignas(128) char As[16384];   // [128 rows][128B] swizzled bf16
    __shared__ alignas(128) char Bs[16384];
    const int tid = threadIdx.x;
    const int lane = tid & 63;
    const int w = tid >> 6;                   // 0..7
    const int wr = w >> 2, wc = w & 3;
    const int r15 = lane & 15, q4 = lane >> 4;
    const int sl8 = lane >> 3;
    const int scol = (((lane & 7) * 16) ^ (sl8 << 4)) >> 1;

    f32x4 acc[4][2] = {};

    for (int k0 = 0; k0 < 1024; k0 += 64) {
        #pragma unroll
        for (int rr = 0; rr < 2; ++rr) {
            int r = rr * 64 + w * 8 + sl8;
            gl2lds16(A  + (size_t)(bm * 128 + r) * 1024 + k0 + scol, &As[(rr * 64 + w * 8) * 128]);
            gl2lds16(Bm + (size_t)(bn * 128 + r) * 1024 + k0 + scol, &Bs[(rr * 64 + w * 8) * 128]);
        }
        asm volatile("s_waitcnt vmcnt(0)" ::: "memory");
        RAW_BARRIER();

        #pragma unroll
        for (int kk = 0; kk < 2; ++kk) {
            bf16x8 af[4], bfr[2];
            #pragma unroll
            for (int m = 0; m < 4; ++m) {
                int row = wr * 64 + m * 16 + r15;
                af[m] = *(const bf16x8*)(&As[row * 128 + ((kk * 64 + q4 * 16) ^ ((row & 7) << 4))]);
            }
            #pragma unroll
            for (int n = 0; n < 2; ++n) {
                int row = wc * 32 + n * 16 + r15;
                bfr[n] = *(const bf16x8*)(&Bs[row * 128 + ((kk * 64 + q4 * 16) ^ ((row & 7) << 4))]);
            }
            #pragma unroll
            for (int m = 0; m < 4; ++m)
                #pragma unroll
                for (int n = 0; n < 2; ++n)
                    acc[m][n] = MFMA32(af[m], bfr[n], acc[m][n]);
        }
        RAW_BARRIER();
    }
    // loop ends with barrier after all reads: LDS free as wave-private scratch

    const size_t seg = (size_t)32 * 2048 * 64;
    const int which = bn >> 3;
    const int row0 = bm * 128 + wr * 64;      // 64 t-rows
    const int col0w = bn * 128 + wc * 32;     // 32 d-cols
    char* ep = ((w & 4) ? Bs : As) + (w & 3) * 4096;   // wave-private 4KB

    if (which == 2) {
        // V: transpose to [d 32][t 64 x2B=128B] (permuted t), then 16B row stores
        #pragma unroll
        for (int m = 0; m < 4; ++m)
            #pragma unroll
            for (int n = 0; n < 2; ++n)
                #pragma unroll
                for (int i = 0; i < 4; ++i) {
                    int dl = n * 16 + r15;                 // 0..31
                    int trow = m * 16 + q4 * 4 + i;        // 0..63
                    int blk = (trow >> 2) & 7;
                    int npos = (blk < 4) ? (blk << 1) : ((blk << 1) - 7);
                    int tcol = (trow & 32) | (npos << 2) | (trow & 3);
                    *(ushort*)(ep + dl * 128 + ((tcol * 2) ^ ((dl & 7) << 4))) =
                        f2bf(acc[m][n][i]);
                }
        const int head = (col0w & 1023) >> 6;
        const int d0 = col0w & 63;                          // 0 or 32
        const int bidx = row0 >> 11;
        const int t0 = row0 & 2047;
        #pragma unroll
        for (int j = 0; j < 4; ++j) {
            int d = (lane >> 3) + j * 8;                    // 0..31
            int c = lane & 7;
            bf16x8 vv = *(const bf16x8*)(ep + d * 128 + ((c * 16) ^ ((d & 7) << 4)));
            *(bf16x8*)(&Qbase[2 * seg + ((size_t)(bidx * 16 + head) * 64 + d0 + d) * 2048 +
                              t0 + c * 8]) = vv;
        }
    } else {
        // Q/K: transpose to [t 64][d 32 x2B=64B], then 8B half-row stores
        const float sc = (which == 0) ? 0.045084439f : 1.0f;  // (1/sqrt(1024))*log2e
        #pragma unroll
        for (int m = 0; m < 4; ++m)
            #pragma unroll
            for (int n = 0; n < 2; ++n)
                #pragma unroll
                for (int i = 0; i < 4; ++i) {
                    int row = m * 16 + q4 * 4 + i;          // 0..63
                    int colb = (n * 16 + r15) * 2;          // 0..62
                    *(ushort*)(ep + row * 64 + (colb ^ ((row & 3) << 4))) =
                        f2bf(acc[m][n][i] * sc);
                }
        const int head = (col0w & 1023) >> 6;
        const int dhalf = col0w & 63;                       // 0 or 32
        #pragma unroll
        for (int j = 0; j < 8; ++j) {
            int row = (lane >> 3) + j * 8;                  // 0..63
            bf16x4 vv = *(const bf16x4*)(ep + row * 64 +
                                         (((lane & 7) * 8) ^ ((row & 3) << 4)));
            int grow = row0 + row;
            int bidx = grow >> 11;
            int t = grow & 2047;
            *(bf16x4*)(&Qbase[(size_t)which * seg +
                              (((size_t)(bidx * 16 + head) * 2048 + t) * 64) + dhalf +
                              (lane & 7) * 4]) = vv;
        }
    }
}

// ---------------- O-projection GEMM: single-buffer, 2D grid (FROZEN) -------------
__global__ __launch_bounds__(256) void gemm_o(const ushort* __restrict__ A,
                                              const ushort* __restrict__ Bm,
                                              float* __restrict__ C) {
    const int bm = blockIdx.x;
    const int bn = blockIdx.y;                    // 0..15
    __shared__ alignas(128) char As[16384];
    __shared__ alignas(128) char Bs[8192];
    const int tid = threadIdx.x;
    const int lane = tid & 63;
    const int w = tid >> 6;
    const int wr = w >> 1, wc = w & 1;
    const int r15 = lane & 15, q4 = lane >> 4;
    const int sl8 = lane >> 3;
    const int scol = (((lane & 7) * 16) ^ (sl8 << 4)) >> 1;

    f32x4 acc[4][2] = {};

    for (int k0 = 0; k0 < 1024; k0 += 64) {
        #pragma unroll
        for (int rr = 0; rr < 4; ++rr) {
            int r = w * 32 + rr * 8 + sl8;
            gl2lds16(A + (size_t)(bm * 128 + r) * 1024 + k0 + scol, &As[(w * 32 + rr * 8) * 128]);
        }
        #pragma unroll
        for (int rr = 0; rr < 2; ++rr) {
            int r = w * 16 + rr * 8 + sl8;
            gl2lds16(Bm + (size_t)(bn * 64 + r) * 1024 + k0 + scol, &Bs[(w * 16 + rr * 8) * 128]);
        }
        asm volatile("s_waitcnt vmcnt(0)" ::: "memory");
        RAW_BARRIER();

        #pragma unroll
        for (int kk = 0; kk < 2; ++kk) {
            bf16x8 af[4], bfr[2];
            #pragma unroll
            for (int m = 0; m < 4; ++m) {
                int row = wr * 64 + m * 16 + r15;
                af[m] = *(const bf16x8*)(&As[row * 128 + ((kk * 64 + q4 * 16) ^ ((row & 7) << 4))]);
            }
            #pragma unroll
            for (int n = 0; n < 2; ++n) {
                int row = wc * 32 + n * 16 + r15;
                bfr[n] = *(const bf16x8*)(&Bs[row * 128 + ((kk * 64 + q4 * 16) ^ ((row & 7) << 4))]);
            }
            #pragma unroll
            for (int m = 0; m < 4; ++m)
                #pragma unroll
                for (int n = 0; n < 2; ++n)
                    acc[m][n] = MFMA32(af[m], bfr[n], acc[m][n]);
        }
        RAW_BARRIER();
    }

    const int row0 = bm * 128 + wr * 64;
    const int col0 = bn * 64 + wc * 32;
    #pragma unroll
    for (int m = 0; m < 4; ++m)
        #pragma unroll
        for (int n = 0; n < 2; ++n)
            #pragma unroll
            for (int i = 0; i < 4; ++i)
                C[(size_t)(row0 + m * 16 + q4 * 4 + i) * 1024 + col0 + n * 16 + r15] =
                    acc[m][n][i];
}

// ------- flash attention: kv-split, b128 V reads, MFMA row-sum (FROZEN) ----------
__global__ __launch_bounds__(1024) void attn_fwd(const ushort* __restrict__ Qh,
                                                 const ushort* __restrict__ Kh,
                                                 const ushort* __restrict__ Vt,
                                                 ushort* __restrict__ Ob) {
    const int bh = blockIdx.x;
    const int qt = blockIdx.y;
    const int tid = threadIdx.x;
    const int lane = tid & 63, w = tid >> 6;
    const int grp = w >> 3, wl = w & 7;
    const int r15 = lane & 15, q4 = lane >> 4;

    const ushort* Qp = Qh + (size_t)bh * T_SZ * HEAD;
    const ushort* Kp = Kh + (size_t)bh * T_SZ * HEAD;
    const ushort* Vp = Vt + (size_t)bh * HEAD * T_SZ;

    __shared__ alignas(16) char SMEM[65536];
    char* Kbuf = SMEM + grp * 32768;
    char* Vbuf = Kbuf + 16384;

    const int srow = wl * 8 + (lane >> 3);
    const int sslot = (lane & 7) * 16;
    const int ssb = (sslot ^ ((srow & 7) << 4)) >> 1;
    const int kvbase = grp << 10;

    const int q0 = qt * 256 + wl * 32;
    bf16x8 qf[2][2];
    #pragma unroll
    for (int cc = 0; cc < 2; ++cc) {
        qf[cc][0] = *(const bf16x8*)(&Qp[(size_t)(q0 + cc * 16 + r15) * 64 + q4 * 8]);
        qf[cc][1] = *(const bf16x8*)(&Qp[(size_t)(q0 + cc * 16 + r15) * 64 + 32 + q4 * 8]);
    }

    const bf16x8 ones8 = {0x3F80, 0x3F80, 0x3F80, 0x3F80, 0x3F80, 0x3F80, 0x3F80, 0x3F80};

    f32x4 acc[2][4] = {};
    f32x4 acc_l[2] = {};

    #define STAGE(buf, kv0)                                                      \
        {                                                                        \
            gl2lds16(Kp + (size_t)(kvbase + (kv0) + srow) * 64 + ssb,            \
                     Kbuf + (buf) * 8192 + wl * 8 * 128);                        \
            gl2lds16(Vp + (size_t)srow * 2048 + kvbase + (kv0) + ssb,            \
                     Vbuf + (buf) * 8192 + wl * 8 * 128);                        \
        }

    STAGE(0, 0);
    int cur = 0;
    for (int it = 0; it < 16; ++it) {
        STAGE(cur ^ 1, ((it + 1) & 15) * 64);
        asm volatile("s_waitcnt vmcnt(2)" ::: "memory");
        RAW_BARRIER();

        const char* Ks = Kbuf + cur * 8192;
        const char* Vs = Vbuf + cur * 8192;

        bf16x8 kf[4][2];
        #pragma unroll
        for (int t4 = 0; t4 < 4; ++t4) {
            int row = t4 * 16 + r15;
            int sw = (row & 7) << 4;
            kf[t4][0] = *(const bf16x8*)(&Ks[row * 128 + ((q4 * 16) ^ sw)]);
            kf[t4][1] = *(const bf16x8*)(&Ks[row * 128 + ((64 + q4 * 16) ^ sw)]);
        }
        bf16x8 vf8[2][4];
        #pragma unroll
        for (int dt = 0; dt < 4; ++dt) {
            int row = dt * 16 + r15;
            int sw = (row & 7) << 4;
            #pragma unroll
            for (int t32 = 0; t32 < 2; ++t32)
                vf8[t32][dt] = *(const bf16x8*)(&Vs[row * 128 + ((t32 * 64 + q4 * 16) ^ sw)]);
        }

        f32x4 z[2][4];
        #pragma unroll
        for (int cc = 0; cc < 2; ++cc)
            #pragma unroll
            for (int t4 = 0; t4 < 4; ++t4) {
                f32x4 zz = {};
                zz = MFMA32(kf[t4][0], qf[cc][0], zz);
                zz = MFMA32(kf[t4][1], qf[cc][1], zz);
                z[cc][t4] = zz;
            }

        bf16x8 pb8[2][2];
        #pragma unroll
        for (int cc = 0; cc < 2; ++cc)
            #pragma unroll
            for (int t32 = 0; t32 < 2; ++t32)
                #pragma unroll
                for (int i = 0; i < 4; ++i) {
                    pb8[cc][t32][i]     = (short)f2bf_fast(exp2fast(z[cc][2 * t32][i]));
                    pb8[cc][t32][4 + i] = (short)f2bf_fast(exp2fast(z[cc][2 * t32 + 1][i]));
                }

        #pragma unroll
        for (int t32 = 0; t32 < 2; ++t32) {
            #pragma unroll
            for (int dt = 0; dt < 4; ++dt)
                #pragma unroll
                for (int cc = 0; cc < 2; ++cc)
                    acc[cc][dt] = MFMA32(vf8[t32][dt], pb8[cc][t32], acc[cc][dt]);
            #pragma unroll
            for (int cc = 0; cc < 2; ++cc)
                acc_l[cc] = MFMA32(ones8, pb8[cc][t32], acc_l[cc]);
        }

        RAW_BARRIER();
        cur ^= 1;
    }
    #undef STAGE

    asm volatile("s_waitcnt vmcnt(0)" ::: "memory");
    __syncthreads();

    float l0 = acc_l[0][0], l1 = acc_l[1][0];
    {
        float* MB = (float*)SMEM;
        #pragma unroll
        for (int rnd = 0; rnd < 2; ++rnd) {
            __syncthreads();
            if (grp == 1 && (wl >> 2) == rnd) {
                float* p = MB + (((wl & 3) * 64 + lane) * 34);
                #pragma unroll
                for (int cc = 0; cc < 2; ++cc)
                    #pragma unroll
                    for (int dt = 0; dt < 4; ++dt) {
                        *(float2*)(p + (cc * 4 + dt) * 4)     = make_float2(acc[cc][dt][0], acc[cc][dt][1]);
                        *(float2*)(p + (cc * 4 + dt) * 4 + 2) = make_float2(acc[cc][dt][2], acc[cc][dt][3]);
                    }
                *(float2*)(p + 32) = make_float2(l0, l1);
            }
            __syncthreads();
            if (grp == 0 && (wl >> 2) == rnd) {
                const float* p = MB + (((wl & 3) * 64 + lane) * 34);
                #pragma unroll
                for (int cc = 0; cc < 2; ++cc)
                    #pragma unroll
                    for (int dt = 0; dt < 4; ++dt)
                        #pragma unroll
                        for (int i = 0; i < 4; ++i)
                            acc[cc][dt][i] += p[(cc * 4 + dt) * 4 + i];
                l0 += p[32];
                l1 += p[33];
            }
        }
    }

    if (grp == 0) {
        const int b = bh >> 4, h = bh & 15;
        #pragma unroll
        for (int cc = 0; cc < 2; ++cc) {
            float inv = 1.0f / (cc ? l1 : l0);
            int q = q0 + cc * 16 + r15;
            #pragma unroll
            for (int dt = 0; dt < 4; ++dt) {
                ushort4 o;
                o.x = f2bf(acc[cc][dt][0] * inv);
                o.y = f2bf(acc[cc][dt][1] * inv);
                o.z = f2bf(acc[cc][dt][2] * inv);
                o.w = f2bf(acc[cc][dt][3] * inv);
                *(ushort4*)(&Ob[((size_t)(b * T_SZ + q)) * KD + h * HEAD + dt * 16 + q4 * 4]) = o;
            }
        }
    }
}

extern "C" void kernel_launch(void* const* d_in, const int* in_sizes, int n_in,
                              void* d_out, int out_size, void* d_ws, size_t ws_size,
                              hipStream_t stream) {
    const float* x  = (const float*)d_in[0];
    const float* Wq = (const float*)d_in[1];
    const float* Wk = (const float*)d_in[2];
    const float* Wv = (const float*)d_in[3];
    const float* Wo = (const float*)d_in[4];

    char* ws = (char*)d_ws;
    const size_t MB = 1024 * 1024;
    ushort* xb    = (ushort*)(ws + 0);
    ushort* Wqkvb = (ushort*)(ws + 8  * MB);
    ushort* Wob   = Wqkvb + 3 * (size_t)KD * KD;
    ushort* Qh    = (ushort*)(ws + 16 * MB);
    ushort* Kh    = (ushort*)(ws + 24 * MB);
    ushort* VhT   = (ushort*)(ws + 32 * MB);
    ushort* Ob    = (ushort*)(ws + 40 * MB);

    {
        int total4 = (M_TOT * KD) / 4 + KD * KD;
        cvt_all<<<total4 / 256, 256, 0, stream>>>(x, Wq, Wk, Wv, Wo, xb, Wqkvb);
    }

    gemm_qkv<<<dim3(32, 24), 512, 0, stream>>>(xb, Wqkvb, Qh);
    attn_fwd<<<dim3(32, 8), 1024, 0, stream>>>(Qh, Kh, VhT, Ob);
    gemm_o<<<dim3(32, 16), 256, 0, stream>>>(Ob, Wob, (float*)d_out);
}

// Round 23
// 99.516 us; speedup vs baseline: 1.0998x; 1.0070x over previous
//
#include <hip/hip_runtime.h>
#include <hip/hip_bf16.h>

#define N_HEADS 16
#define HEAD 64
#define B_SZ 2
#define T_SZ 2048
#define KD 1024
#define M_TOT (B_SZ * T_SZ)   // 4096

typedef short bf16x8 __attribute__((ext_vector_type(8)));
typedef short bf16x4 __attribute__((ext_vector_type(4)));
typedef float f32x4  __attribute__((ext_vector_type(4)));

#define MFMA32(a, b, c) __builtin_amdgcn_mfma_f32_16x16x32_bf16((a), (b), (c), 0, 0, 0)

__device__ __forceinline__ ushort f2bf(float f) {
    __hip_bfloat16 h = __float2bfloat16(f);
    return *reinterpret_cast<ushort*>(&h);
}

// fast bf16 round (round-half-up) for positive finite values: 2 VALU ops
__device__ __forceinline__ ushort f2bf_fast(float f) {
    return (ushort)((__float_as_uint(f) + 0x8000u) >> 16);
}

__device__ __forceinline__ float exp2fast(float x) {
#if __has_builtin(__builtin_amdgcn_exp2f)
    return __builtin_amdgcn_exp2f(x);
#else
    return exp2f(x);
#endif
}

__device__ __forceinline__ void gl2lds16(const ushort* g, void* l) {
    __builtin_amdgcn_global_load_lds(
        (const __attribute__((address_space(1))) unsigned int*)g,
        (__attribute__((address_space(3))) unsigned int*)l, 16, 0, 0);
}

#define RAW_BARRIER() do { asm volatile("" ::: "memory"); \
                           __builtin_amdgcn_s_barrier();  \
                           asm volatile("" ::: "memory"); } while (0)

// ---------------- fused fp32 -> bf16 convert (x + all 4 weights) ----------------
__global__ void cvt_all(const float* __restrict__ x,
                        const float* __restrict__ Wq, const float* __restrict__ Wk,
                        const float* __restrict__ Wv, const float* __restrict__ Wo,
                        ushort* __restrict__ xb, ushort* __restrict__ wb) {
    const int NX = (M_TOT * KD) / 4;
    const int NW = (KD * KD) / 4;
    int i = blockIdx.x * blockDim.x + threadIdx.x;
    float4 v;
    ushort* dst;
    if (i < NX) {
        v = reinterpret_cast<const float4*>(x)[i];
        dst = xb + (size_t)i * 4;
    } else {
        int j = i - NX;
        int w = j >> 18;
        int r = j & (NW - 1);
        const float* s = (w == 0) ? Wq : (w == 1) ? Wk : (w == 2) ? Wv : Wo;
        v = reinterpret_cast<const float4*>(s)[r];
        dst = wb + (size_t)w * KD * KD + (size_t)r * 4;
    }
    ushort4 o;
    o.x = f2bf(v.x); o.y = f2bf(v.y); o.z = f2bf(v.z); o.w = f2bf(v.w);
    *reinterpret_cast<ushort4*>(dst) = o;
}

// ------------- QKV GEMM: 8 waves/block (2x4), 128x128 tile (FROZEN) --------------
__global__ __launch_bounds__(512) void gemm_qkv(const ushort* __restrict__ A,
                                                const ushort* __restrict__ Bm,
                                                ushort* __restrict__ Qbase) {
    const int bm = blockIdx.x;
    const int bn = blockIdx.y;
    __shared__ alignas(128) char As[16384];   // [128 rows][128B] swizzled bf16
    __shared__ alignas(128) char Bs[16384];
    const int tid = threadIdx.x;
    const int lane = tid & 63;
    const int w = tid >> 6;                   // 0..7
    const int wr = w >> 2, wc = w & 3;
    const int r15 = lane & 15, q4 = lane >> 4;
    const int sl8 = lane >> 3;
    const int scol = (((lane & 7) * 16) ^ (sl8 << 4)) >> 1;

    f32x4 acc[4][2] = {};

    for (int k0 = 0; k0 < 1024; k0 += 64) {
        #pragma unroll
        for (int rr = 0; rr < 2; ++rr) {
            int r = rr * 64 + w * 8 + sl8;
            gl2lds16(A  + (size_t)(bm * 128 + r) * 1024 + k0 + scol, &As[(rr * 64 + w * 8) * 128]);
            gl2lds16(Bm + (size_t)(bn * 128 + r) * 1024 + k0 + scol, &Bs[(rr * 64 + w * 8) * 128]);
        }
        asm volatile("s_waitcnt vmcnt(0)" ::: "memory");
        RAW_BARRIER();

        #pragma unroll
        for (int kk = 0; kk < 2; ++kk) {
            bf16x8 af[4], bfr[2];
            #pragma unroll
            for (int m = 0; m < 4; ++m) {
                int row = wr * 64 + m * 16 + r15;
                af[m] = *(const bf16x8*)(&As[row * 128 + ((kk * 64 + q4 * 16) ^ ((row & 7) << 4))]);
            }
            #pragma unroll
            for (int n = 0; n < 2; ++n) {
                int row = wc * 32 + n * 16 + r15;
                bfr[n] = *(const bf16x8*)(&Bs[row * 128 + ((kk * 64 + q4 * 16) ^ ((row & 7) << 4))]);
            }
            #pragma unroll
            for (int m = 0; m < 4; ++m)
                #pragma unroll
                for (int n = 0; n < 2; ++n)
                    acc[m][n] = MFMA32(af[m], bfr[n], acc[m][n]);
        }
        RAW_BARRIER();
    }
    // loop ends with barrier after all reads: LDS free as wave-private scratch

    const size_t seg = (size_t)32 * 2048 * 64;
    const int which = bn >> 3;
    const int row0 = bm * 128 + wr * 64;      // 64 t-rows
    const int col0w = bn * 128 + wc * 32;     // 32 d-cols
    char* ep = ((w & 4) ? Bs : As) + (w & 3) * 4096;   // wave-private 4KB

    if (which == 2) {
        // V: transpose to [d 32][t 64 x2B=128B] (permuted t), then 16B row stores
        #pragma unroll
        for (int m = 0; m < 4; ++m)
            #pragma unroll
            for (int n = 0; n < 2; ++n)
                #pragma unroll
                for (int i = 0; i < 4; ++i) {
                    int dl = n * 16 + r15;                 // 0..31
                    int trow = m * 16 + q4 * 4 + i;        // 0..63
                    int blk = (trow >> 2) & 7;
                    int npos = (blk < 4) ? (blk << 1) : ((blk << 1) - 7);
                    int tcol = (trow & 32) | (npos << 2) | (trow & 3);
                    *(ushort*)(ep + dl * 128 + ((tcol * 2) ^ ((dl & 7) << 4))) =
                        f2bf(acc[m][n][i]);
                }
        const int head = (col0w & 1023) >> 6;
        const int d0 = col0w & 63;                          // 0 or 32
        const int bidx = row0 >> 11;
        const int t0 = row0 & 2047;
        #pragma unroll
        for (int j = 0; j < 4; ++j) {
            int d = (lane >> 3) + j * 8;                    // 0..31
            int c = lane & 7;
            bf16x8 vv = *(const bf16x8*)(ep + d * 128 + ((c * 16) ^ ((d & 7) << 4)));
            *(bf16x8*)(&Qbase[2 * seg + ((size_t)(bidx * 16 + head) * 64 + d0 + d) * 2048 +
                              t0 + c * 8]) = vv;
        }
    } else {
        // Q/K: transpose to [t 64][d 32 x2B=64B], then 8B half-row stores
        const float sc = (which == 0) ? 0.045084439f : 1.0f;  // (1/sqrt(1024))*log2e
        #pragma unroll
        for (int m = 0; m < 4; ++m)
            #pragma unroll
            for (int n = 0; n < 2; ++n)
                #pragma unroll
                for (int i = 0; i < 4; ++i) {
                    int row = m * 16 + q4 * 4 + i;          // 0..63
                    int colb = (n * 16 + r15) * 2;          // 0..62
                    *(ushort*)(ep + row * 64 + (colb ^ ((row & 3) << 4))) =
                        f2bf(acc[m][n][i] * sc);
                }
        const int head = (col0w & 1023) >> 6;
        const int dhalf = col0w & 63;                       // 0 or 32
        #pragma unroll
        for (int j = 0; j < 8; ++j) {
            int row = (lane >> 3) + j * 8;                  // 0..63
            bf16x4 vv = *(const bf16x4*)(ep + row * 64 +
                                         (((lane & 7) * 8) ^ ((row & 3) << 4)));
            int grow = row0 + row;
            int bidx = grow >> 11;
            int t = grow & 2047;
            *(bf16x4*)(&Qbase[(size_t)which * seg +
                              (((size_t)(bidx * 16 + head) * 2048 + t) * 64) + dhalf +
                              (lane & 7) * 4]) = vv;
        }
    }
}

// ------------- O-projection GEMM: 8 waves/block (2x4), 128x64 tile ---------------
// Mirror of the qkv occupancy fix: 512 thr, wave tile 64x16, acc[4][1].
// 2 blocks/CU x 8 waves = 16 waves/CU (4/SIMD) vs 8 before.
__global__ __launch_bounds__(512) void gemm_o(const ushort* __restrict__ A,
                                              const ushort* __restrict__ Bm,
                                              float* __restrict__ C) {
    const int bm = blockIdx.x;
    const int bn = blockIdx.y;                    // 0..15
    __shared__ alignas(128) char As[16384];       // [128][128B]
    __shared__ alignas(128) char Bs[8192];        // [64][128B]
    const int tid = threadIdx.x;
    const int lane = tid & 63;
    const int w = tid >> 6;                       // 0..7
    const int wr = w >> 2, wc = w & 3;            // 2 row-halves x 4 col-quarters
    const int r15 = lane & 15, q4 = lane >> 4;
    const int sl8 = lane >> 3;
    const int scol = (((lane & 7) * 16) ^ (sl8 << 4)) >> 1;

    f32x4 acc[4] = {};

    for (int k0 = 0; k0 < 1024; k0 += 64) {
        #pragma unroll
        for (int rr = 0; rr < 2; ++rr) {
            int r = rr * 64 + w * 8 + sl8;
            gl2lds16(A + (size_t)(bm * 128 + r) * 1024 + k0 + scol, &As[(rr * 64 + w * 8) * 128]);
        }
        {
            int r = w * 8 + sl8;
            gl2lds16(Bm + (size_t)(bn * 64 + r) * 1024 + k0 + scol, &Bs[(w * 8) * 128]);
        }
        asm volatile("s_waitcnt vmcnt(0)" ::: "memory");
        RAW_BARRIER();

        #pragma unroll
        for (int kk = 0; kk < 2; ++kk) {
            bf16x8 af[4], bfr;
            #pragma unroll
            for (int m = 0; m < 4; ++m) {
                int row = wr * 64 + m * 16 + r15;
                af[m] = *(const bf16x8*)(&As[row * 128 + ((kk * 64 + q4 * 16) ^ ((row & 7) << 4))]);
            }
            {
                int row = wc * 16 + r15;
                bfr = *(const bf16x8*)(&Bs[row * 128 + ((kk * 64 + q4 * 16) ^ ((row & 7) << 4))]);
            }
            #pragma unroll
            for (int m = 0; m < 4; ++m)
                acc[m] = MFMA32(af[m], bfr, acc[m]);
        }
        RAW_BARRIER();
    }

    const int row0 = bm * 128 + wr * 64;
    const int col0 = bn * 64 + wc * 16;
    #pragma unroll
    for (int m = 0; m < 4; ++m)
        #pragma unroll
        for (int i = 0; i < 4; ++i)
            C[(size_t)(row0 + m * 16 + q4 * 4 + i) * 1024 + col0 + r15] = acc[m][i];
}

// ------- flash attention: kv-split, b128 V reads, MFMA row-sum (FROZEN) ----------
__global__ __launch_bounds__(1024) void attn_fwd(const ushort* __restrict__ Qh,
                                                 const ushort* __restrict__ Kh,
                                                 const ushort* __restrict__ Vt,
                                                 ushort* __restrict__ Ob) {
    const int bh = blockIdx.x;
    const int qt = blockIdx.y;
    const int tid = threadIdx.x;
    const int lane = tid & 63, w = tid >> 6;
    const int grp = w >> 3, wl = w & 7;
    const int r15 = lane & 15, q4 = lane >> 4;

    const ushort* Qp = Qh + (size_t)bh * T_SZ * HEAD;
    const ushort* Kp = Kh + (size_t)bh * T_SZ * HEAD;
    const ushort* Vp = Vt + (size_t)bh * HEAD * T_SZ;

    __shared__ alignas(16) char SMEM[65536];
    char* Kbuf = SMEM + grp * 32768;
    char* Vbuf = Kbuf + 16384;

    const int srow = wl * 8 + (lane >> 3);
    const int sslot = (lane & 7) * 16;
    const int ssb = (sslot ^ ((srow & 7) << 4)) >> 1;
    const int kvbase = grp << 10;

    const int q0 = qt * 256 + wl * 32;
    bf16x8 qf[2][2];
    #pragma unroll
    for (int cc = 0; cc < 2; ++cc) {
        qf[cc][0] = *(const bf16x8*)(&Qp[(size_t)(q0 + cc * 16 + r15) * 64 + q4 * 8]);
        qf[cc][1] = *(const bf16x8*)(&Qp[(size_t)(q0 + cc * 16 + r15) * 64 + 32 + q4 * 8]);
    }

    const bf16x8 ones8 = {0x3F80, 0x3F80, 0x3F80, 0x3F80, 0x3F80, 0x3F80, 0x3F80, 0x3F80};

    f32x4 acc[2][4] = {};
    f32x4 acc_l[2] = {};

    #define STAGE(buf, kv0)                                                      \
        {                                                                        \
            gl2lds16(Kp + (size_t)(kvbase + (kv0) + srow) * 64 + ssb,            \
                     Kbuf + (buf) * 8192 + wl * 8 * 128);                        \
            gl2lds16(Vp + (size_t)srow * 2048 + kvbase + (kv0) + ssb,            \
                     Vbuf + (buf) * 8192 + wl * 8 * 128);                        \
        }

    STAGE(0, 0);
    int cur = 0;
    for (int it = 0; it < 16; ++it) {
        STAGE(cur ^ 1, ((it + 1) & 15) * 64);
        asm volatile("s_waitcnt vmcnt(2)" ::: "memory");
        RAW_BARRIER();

        const char* Ks = Kbuf + cur * 8192;
        const char* Vs = Vbuf + cur * 8192;

        bf16x8 kf[4][2];
        #pragma unroll
        for (int t4 = 0; t4 < 4; ++t4) {
            int row = t4 * 16 + r15;
            int sw = (row & 7) << 4;
            kf[t4][0] = *(const bf16x8*)(&Ks[row * 128 + ((q4 * 16) ^ sw)]);
            kf[t4][1] = *(const bf16x8*)(&Ks[row * 128 + ((64 + q4 * 16) ^ sw)]);
        }
        bf16x8 vf8[2][4];
        #pragma unroll
        for (int dt = 0; dt < 4; ++dt) {
            int row = dt * 16 + r15;
            int sw = (row & 7) << 4;
            #pragma unroll
            for (int t32 = 0; t32 < 2; ++t32)
                vf8[t32][dt] = *(const bf16x8*)(&Vs[row * 128 + ((t32 * 64 + q4 * 16) ^ sw)]);
        }

        f32x4 z[2][4];
        #pragma unroll
        for (int cc = 0; cc < 2; ++cc)
            #pragma unroll
            for (int t4 = 0; t4 < 4; ++t4) {
                f32x4 zz = {};
                zz = MFMA32(kf[t4][0], qf[cc][0], zz);
                zz = MFMA32(kf[t4][1], qf[cc][1], zz);
                z[cc][t4] = zz;
            }

        bf16x8 pb8[2][2];
        #pragma unroll
        for (int cc = 0; cc < 2; ++cc)
            #pragma unroll
            for (int t32 = 0; t32 < 2; ++t32)
                #pragma unroll
                for (int i = 0; i < 4; ++i) {
                    pb8[cc][t32][i]     = (short)f2bf_fast(exp2fast(z[cc][2 * t32][i]));
                    pb8[cc][t32][4 + i] = (short)f2bf_fast(exp2fast(z[cc][2 * t32 + 1][i]));
                }

        #pragma unroll
        for (int t32 = 0; t32 < 2; ++t32) {
            #pragma unroll
            for (int dt = 0; dt < 4; ++dt)
                #pragma unroll
                for (int cc = 0; cc < 2; ++cc)
                    acc[cc][dt] = MFMA32(vf8[t32][dt], pb8[cc][t32], acc[cc][dt]);
            #pragma unroll
            for (int cc = 0; cc < 2; ++cc)
                acc_l[cc] = MFMA32(ones8, pb8[cc][t32], acc_l[cc]);
        }

        RAW_BARRIER();
        cur ^= 1;
    }
    #undef STAGE

    asm volatile("s_waitcnt vmcnt(0)" ::: "memory");
    __syncthreads();

    float l0 = acc_l[0][0], l1 = acc_l[1][0];
    {
        float* MB = (float*)SMEM;
        #pragma unroll
        for (int rnd = 0; rnd < 2; ++rnd) {
            __syncthreads();
            if (grp == 1 && (wl >> 2) == rnd) {
                float* p = MB + (((wl & 3) * 64 + lane) * 34);
                #pragma unroll
                for (int cc = 0; cc < 2; ++cc)
                    #pragma unroll
                    for (int dt = 0; dt < 4; ++dt) {
                        *(float2*)(p + (cc * 4 + dt) * 4)     = make_float2(acc[cc][dt][0], acc[cc][dt][1]);
                        *(float2*)(p + (cc * 4 + dt) * 4 + 2) = make_float2(acc[cc][dt][2], acc[cc][dt][3]);
                    }
                *(float2*)(p + 32) = make_float2(l0, l1);
            }
            __syncthreads();
            if (grp == 0 && (wl >> 2) == rnd) {
                const float* p = MB + (((wl & 3) * 64 + lane) * 34);
                #pragma unroll
                for (int cc = 0; cc < 2; ++cc)
                    #pragma unroll
                    for (int dt = 0; dt < 4; ++dt)
                        #pragma unroll
                        for (int i = 0; i < 4; ++i)
                            acc[cc][dt][i] += p[(cc * 4 + dt) * 4 + i];
                l0 += p[32];
                l1 += p[33];
            }
        }
    }

    if (grp == 0) {
        const int b = bh >> 4, h = bh & 15;
        #pragma unroll
        for (int cc = 0; cc < 2; ++cc) {
            float inv = 1.0f / (cc ? l1 : l0);
            int q = q0 + cc * 16 + r15;
            #pragma unroll
            for (int dt = 0; dt < 4; ++dt) {
                ushort4 o;
                o.x = f2bf(acc[cc][dt][0] * inv);
                o.y = f2bf(acc[cc][dt][1] * inv);
                o.z = f2bf(acc[cc][dt][2] * inv);
                o.w = f2bf(acc[cc][dt][3] * inv);
                *(ushort4*)(&Ob[((size_t)(b * T_SZ + q)) * KD + h * HEAD + dt * 16 + q4 * 4]) = o;
            }
        }
    }
}

extern "C" void kernel_launch(void* const* d_in, const int* in_sizes, int n_in,
                              void* d_out, int out_size, void* d_ws, size_t ws_size,
                              hipStream_t stream) {
    const float* x  = (const float*)d_in[0];
    const float* Wq = (const float*)d_in[1];
    const float* Wk = (const float*)d_in[2];
    const float* Wv = (const float*)d_in[3];
    const float* Wo = (const float*)d_in[4];

    char* ws = (char*)d_ws;
    const size_t MB = 1024 * 1024;
    ushort* xb    = (ushort*)(ws + 0);
    ushort* Wqkvb = (ushort*)(ws + 8  * MB);
    ushort* Wob   = Wqkvb + 3 * (size_t)KD * KD;
    ushort* Qh    = (ushort*)(ws + 16 * MB);
    ushort* Kh    = (ushort*)(ws + 24 * MB);
    ushort* VhT   = (ushort*)(ws + 32 * MB);
    ushort* Ob    = (ushort*)(ws + 40 * MB);

    {
        int total4 = (M_TOT * KD) / 4 + KD * KD;
        cvt_all<<<total4 / 256, 256, 0, stream>>>(x, Wq, Wk, Wv, Wo, xb, Wqkvb);
    }

    gemm_qkv<<<dim3(32, 24), 512, 0, stream>>>(xb, Wqkvb, Qh);
    attn_fwd<<<dim3(32, 8), 1024, 0, stream>>>(Qh, Kh, VhT, Ob);
    gemm_o<<<dim3(32, 16), 512, 0, stream>>>(Ob, Wob, (float*)d_out);
}

// Round 25
// 95.751 us; speedup vs baseline: 1.1430x; 1.0393x over previous
//
#include <hip/hip_runtime.h>
#include <hip/hip_bf16.h>

#define N_HEADS 16
#define HEAD 64
#define B_SZ 2
#define T_SZ 2048
#define KD 1024
#define M_TOT (B_SZ * T_SZ)   // 4096

typedef short bf16x8 __attribute__((ext_vector_type(8)));
typedef short bf16x4 __attribute__((ext_vector_type(4)));
typedef float f32x4  __attribute__((ext_vector_type(4)));

#define MFMA32(a, b, c) __builtin_amdgcn_mfma_f32_16x16x32_bf16((a), (b), (c), 0, 0, 0)

__device__ __forceinline__ ushort f2bf(float f) {
    __hip_bfloat16 h = __float2bfloat16(f);
    return *reinterpret_cast<ushort*>(&h);
}

// fast bf16 round (round-half-up) for positive finite values: 2 VALU ops
__device__ __forceinline__ ushort f2bf_fast(float f) {
    return (ushort)((__float_as_uint(f) + 0x8000u) >> 16);
}

__device__ __forceinline__ float exp2fast(float x) {
#if __has_builtin(__builtin_amdgcn_exp2f)
    return __builtin_amdgcn_exp2f(x);
#else
    return exp2f(x);
#endif
}

__device__ __forceinline__ void gl2lds16(const ushort* g, void* l) {
    __builtin_amdgcn_global_load_lds(
        (const __attribute__((address_space(1))) unsigned int*)g,
        (__attribute__((address_space(3))) unsigned int*)l, 16, 0, 0);
}

#define RAW_BARRIER() do { asm volatile("" ::: "memory"); \
                           __builtin_amdgcn_s_barrier();  \
                           asm volatile("" ::: "memory"); } while (0)

// ---------------- fused fp32 -> bf16 convert (x + all 4 weights) ----------------
__global__ void cvt_all(const float* __restrict__ x,
                        const float* __restrict__ Wq, const float* __restrict__ Wk,
                        const float* __restrict__ Wv, const float* __restrict__ Wo,
                        ushort* __restrict__ xb, ushort* __restrict__ wb) {
    const int NX = (M_TOT * KD) / 4;
    const int NW = (KD * KD) / 4;
    int i = blockIdx.x * blockDim.x + threadIdx.x;
    float4 v;
    ushort* dst;
    if (i < NX) {
        v = reinterpret_cast<const float4*>(x)[i];
        dst = xb + (size_t)i * 4;
    } else {
        int j = i - NX;
        int w = j >> 18;
        int r = j & (NW - 1);
        const float* s = (w == 0) ? Wq : (w == 1) ? Wk : (w == 2) ? Wv : Wo;
        v = reinterpret_cast<const float4*>(s)[r];
        dst = wb + (size_t)w * KD * KD + (size_t)r * 4;
    }
    ushort4 o;
    o.x = f2bf(v.x); o.y = f2bf(v.y); o.z = f2bf(v.z); o.w = f2bf(v.w);
    *reinterpret_cast<ushort4*>(dst) = o;
}

// ====== QKV GEMM: 256x256 tile, 8-phase interleave (race-fixed sync) =============
// 8 waves (2x4), wave tile 128x64, BK=64, K=1024 -> 16 K-tiles, 8 super-iters.
// LDS 128KB: A parity buffers at 0/32KB, B at 64/96KB.
// SYNC RULE (attn-proven): vmcnt BEFORE the barrier that opens a read window --
// every wave retires its OWN staging loads pre-barrier, so post-barrier ALL
// waves' writes are visible. Staging issued early (p1-p2 / p5-p6); full drain
// vmcnt(0) at p4/p8 end, covered by ~2-3 MFMA-cluster phases of compute.
__global__ __launch_bounds__(512) void gemm_qkv(const ushort* __restrict__ A,
                                                const ushort* __restrict__ Bm,
                                                ushort* __restrict__ Qbase) {
    const int bm = blockIdx.x;     // 0..15 (M tiles of 256)
    const int bn = blockIdx.y;     // 0..11 (N tiles of 256)
    __shared__ alignas(128) char SM[131072];
    const int tid = threadIdx.x;
    const int lane = tid & 63;
    const int w = tid >> 6;        // 0..7
    const int wr = w >> 2, wc = w & 3;
    const int r15 = lane & 15, q4 = lane >> 4;
    const int sl8 = lane >> 3;
    const int scol = (((lane & 7) * 16) ^ (sl8 << 4)) >> 1;

    f32x4 acc[8][4] = {};

#define QSTAGE_A(s, kofs, h)                                                     \
    { _Pragma("unroll")                                                          \
      for (int inst = 0; inst < 2; ++inst) {                                     \
          int lr = (h) * 128 + w * 16 + inst * 8;                                \
          gl2lds16(A + (size_t)(bm * 256 + lr + sl8) * 1024 + (kofs) + scol,     \
                   SM + (s) * 32768 + (size_t)lr * 128);                         \
      } }
#define QSTAGE_B(s, kofs, h)                                                     \
    { _Pragma("unroll")                                                          \
      for (int inst = 0; inst < 2; ++inst) {                                     \
          int lr = (h) * 128 + w * 16 + inst * 8;                                \
          gl2lds16(Bm + (size_t)(bn * 256 + lr + sl8) * 1024 + (kofs) + scol,    \
                   SM + 65536 + (s) * 32768 + (size_t)lr * 128);                 \
      } }
#define QLOAD_A(kt, qm)                                                          \
    { const char* Ab_ = SM + (kt) * 32768;                                       \
      _Pragma("unroll") for (int m = 0; m < 4; ++m)                              \
      _Pragma("unroll") for (int kk = 0; kk < 2; ++kk) {                         \
          int row = wr * 128 + (qm) * 64 + m * 16 + r15;                         \
          af[m * 2 + kk] = *(const bf16x8*)(&Ab_[row * 128 +                     \
              ((kk * 64 + q4 * 16) ^ ((row & 7) << 4))]);                        \
      } }
#define QLOAD_B(kt, qn, dstv)                                                    \
    { const char* Bb_ = SM + 65536 + (kt) * 32768;                               \
      _Pragma("unroll") for (int n = 0; n < 2; ++n)                              \
      _Pragma("unroll") for (int kk = 0; kk < 2; ++kk) {                         \
          int row = wc * 64 + (qn) * 32 + n * 16 + r15;                          \
          dstv[n * 2 + kk] = *(const bf16x8*)(&Bb_[row * 128 +                   \
              ((kk * 64 + q4 * 16) ^ ((row & 7) << 4))]);                        \
      } }
#define QMFMA(qm, qn, bv)                                                        \
    { __builtin_amdgcn_s_setprio(1);                                             \
      _Pragma("unroll") for (int m = 0; m < 4; ++m)                              \
      _Pragma("unroll") for (int n = 0; n < 2; ++n)                              \
      _Pragma("unroll") for (int kk = 0; kk < 2; ++kk)                           \
          acc[(qm) * 4 + m][(qn) * 2 + n] =                                      \
              MFMA32(af[m * 2 + kk], bv[n * 2 + kk],                             \
                     acc[(qm) * 4 + m][(qn) * 2 + n]);                           \
      __builtin_amdgcn_s_setprio(0); }

    // prologue: tile 0 -> parity 0; drain + barrier (attn-proven order)
    QSTAGE_A(0, 0, 0); QSTAGE_A(0, 0, 1); QSTAGE_B(0, 0, 0); QSTAGE_B(0, 0, 1);
    asm volatile("s_waitcnt vmcnt(0)" ::: "memory");
    RAW_BARRIER();

    bf16x8 af[8], bf0[4], bf1[4];

    for (int i = 0; i < 8; ++i) {
        const int k1 = (2 * i + 1) * 64;
        const int k2 = ((2 * i + 2) & 15) * 64;   // i=7 wraps to 0 (dummy, drained)
        // ---- read window: tile 2i (parity 0); stage tile 2i+1 (parity 1) ----
        // p1: issue all A staging early
        QSTAGE_A(1, k1, 0); QSTAGE_A(1, k1, 1);
        QLOAD_A(0, 0); QLOAD_B(0, 0, bf0);
        QMFMA(0, 0, bf0);
        RAW_BARRIER();
        // p2: issue all B staging
        QSTAGE_B(1, k1, 0); QSTAGE_B(1, k1, 1);
        QLOAD_B(0, 1, bf1);
        QMFMA(0, 1, bf1);
        RAW_BARRIER();
        // p3
        QLOAD_A(0, 1);
        QMFMA(1, 0, bf0);
        RAW_BARRIER();
        // p4: drain tile-2i+1 loads BEFORE the barrier opening their read window
        QMFMA(1, 1, bf1);
        asm volatile("s_waitcnt vmcnt(0)" ::: "memory");
        RAW_BARRIER();
        // ---- read window: tile 2i+1 (parity 1); stage tile 2i+2 (parity 0) ----
        // p5
        QSTAGE_A(0, k2, 0); QSTAGE_A(0, k2, 1);
        QLOAD_A(1, 0); QLOAD_B(1, 0, bf0);
        QMFMA(0, 0, bf0);
        RAW_BARRIER();
        // p6
        QSTAGE_B(0, k2, 0); QSTAGE_B(0, k2, 1);
        QLOAD_B(1, 1, bf1);
        QMFMA(0, 1, bf1);
        RAW_BARRIER();
        // p7
        QLOAD_A(1, 1);
        QMFMA(1, 0, bf0);
        RAW_BARRIER();
        // p8: drain tile-2i+2 loads before next iter's read window
        QMFMA(1, 1, bf1);
        asm volatile("s_waitcnt vmcnt(0)" ::: "memory");
        RAW_BARRIER();
    }

    // ---- epilogue: per-wave 16KB LDS transpose scratch, coalesced scatter ----
    const size_t seg = (size_t)32 * 2048 * 64;
    const int which = bn >> 2;                 // 0=Q 1=K 2=V (4 tiles per matrix)
    const int head = (bn & 3) * 4 + wc;        // wave cols = one head (64 d)
    const int row0 = bm * 256 + wr * 128;
    const int bidx = row0 >> 11;
    const int t0 = row0 & 2047;
    char* ep = SM + w * 16384;

    if (which == 2) {
        // V: scratch [d 64][t 128 -> 256B rows], permuted t-blocks, swz ^(d&15)<<4
        #pragma unroll
        for (int m = 0; m < 8; ++m)
            #pragma unroll
            for (int nn = 0; nn < 4; ++nn)
                #pragma unroll
                for (int i2 = 0; i2 < 4; ++i2) {
                    int d = nn * 16 + r15;
                    int traw = m * 16 + q4 * 4 + i2;
                    int blk = (traw >> 2) & 7;
                    int npos = (blk < 4) ? (blk << 1) : ((blk << 1) - 7);
                    int tp = (traw & ~31) | (npos << 2) | (traw & 3);
                    *(ushort*)(ep + d * 256 + ((tp * 2) ^ ((d & 15) << 4))) =
                        f2bf(acc[m][nn][i2]);
                }
        #pragma unroll
        for (int j = 0; j < 16; ++j) {
            int d = (lane >> 4) + j * 4;
            int c = lane & 15;
            bf16x8 vv = *(const bf16x8*)(ep + d * 256 + ((c * 16) ^ ((d & 15) << 4)));
            *(bf16x8*)(&Qbase[2 * seg + ((size_t)(bidx * 16 + head) * 64 + d) * 2048 +
                              t0 + c * 8]) = vv;
        }
    } else {
        const float sc = (which == 0) ? 0.045084439f : 1.0f;  // (1/sqrt(1024))*log2e
        // Q/K: scratch [t 128][d 64 -> 128B rows], swz ^(t&7)<<4
        #pragma unroll
        for (int m = 0; m < 8; ++m)
            #pragma unroll
            for (int nn = 0; nn < 4; ++nn)
                #pragma unroll
                for (int i2 = 0; i2 < 4; ++i2) {
                    int t = m * 16 + q4 * 4 + i2;
                    int dby = (nn * 16 + r15) * 2;
                    *(ushort*)(ep + t * 128 + (dby ^ ((t & 7) << 4))) =
                        f2bf(acc[m][nn][i2] * sc);
                }
        #pragma unroll
        for (int j = 0; j < 16; ++j) {
            int row = (lane >> 3) + j * 8;
            bf16x8 vv = *(const bf16x8*)(ep + row * 128 +
                                         (((lane & 7) * 16) ^ ((row & 7) << 4)));
            *(bf16x8*)(&Qbase[(size_t)which * seg +
                              (((size_t)(bidx * 16 + head) * 2048 + t0 + row) * 64) +
                              (lane & 7) * 8]) = vv;
        }
    }
#undef QSTAGE_A
#undef QSTAGE_B
#undef QLOAD_A
#undef QLOAD_B
#undef QMFMA
}

// ------------- O-projection GEMM: 8 waves/block (2x4), 128x64 tile (FROZEN) ------
__global__ __launch_bounds__(512) void gemm_o(const ushort* __restrict__ A,
                                              const ushort* __restrict__ Bm,
                                              float* __restrict__ C) {
    const int bm = blockIdx.x;
    const int bn = blockIdx.y;                    // 0..15
    __shared__ alignas(128) char As[16384];       // [128][128B]
    __shared__ alignas(128) char Bs[8192];        // [64][128B]
    const int tid = threadIdx.x;
    const int lane = tid & 63;
    const int w = tid >> 6;                       // 0..7
    const int wr = w >> 2, wc = w & 3;            // 2 row-halves x 4 col-quarters
    const int r15 = lane & 15, q4 = lane >> 4;
    const int sl8 = lane >> 3;
    const int scol = (((lane & 7) * 16) ^ (sl8 << 4)) >> 1;

    f32x4 acc[4] = {};

    for (int k0 = 0; k0 < 1024; k0 += 64) {
        #pragma unroll
        for (int rr = 0; rr < 2; ++rr) {
            int r = rr * 64 + w * 8 + sl8;
            gl2lds16(A + (size_t)(bm * 128 + r) * 1024 + k0 + scol, &As[(rr * 64 + w * 8) * 128]);
        }
        {
            int r = w * 8 + sl8;
            gl2lds16(Bm + (size_t)(bn * 64 + r) * 1024 + k0 + scol, &Bs[(w * 8) * 128]);
        }
        asm volatile("s_waitcnt vmcnt(0)" ::: "memory");
        RAW_BARRIER();

        #pragma unroll
        for (int kk = 0; kk < 2; ++kk) {
            bf16x8 af[4], bfr;
            #pragma unroll
            for (int m = 0; m < 4; ++m) {
                int row = wr * 64 + m * 16 + r15;
                af[m] = *(const bf16x8*)(&As[row * 128 + ((kk * 64 + q4 * 16) ^ ((row & 7) << 4))]);
            }
            {
                int row = wc * 16 + r15;
                bfr = *(const bf16x8*)(&Bs[row * 128 + ((kk * 64 + q4 * 16) ^ ((row & 7) << 4))]);
            }
            #pragma unroll
            for (int m = 0; m < 4; ++m)
                acc[m] = MFMA32(af[m], bfr, acc[m]);
        }
        RAW_BARRIER();
    }

    const int row0 = bm * 128 + wr * 64;
    const int col0 = bn * 64 + wc * 16;
    #pragma unroll
    for (int m = 0; m < 4; ++m)
        #pragma unroll
        for (int i = 0; i < 4; ++i)
            C[(size_t)(row0 + m * 16 + q4 * 4 + i) * 1024 + col0 + r15] = acc[m][i];
}

// ------- flash attention: kv-split, b128 V reads, MFMA row-sum (FROZEN) ----------
__global__ __launch_bounds__(1024) void attn_fwd(const ushort* __restrict__ Qh,
                                                 const ushort* __restrict__ Kh,
                                                 const ushort* __restrict__ Vt,
                                                 ushort* __restrict__ Ob) {
    const int bh = blockIdx.x;
    const int qt = blockIdx.y;
    const int tid = threadIdx.x;
    const int lane = tid & 63, w = tid >> 6;
    const int grp = w >> 3, wl = w & 7;
    const int r15 = lane & 15, q4 = lane >> 4;

    const ushort* Qp = Qh + (size_t)bh * T_SZ * HEAD;
    const ushort* Kp = Kh + (size_t)bh * T_SZ * HEAD;
    const ushort* Vp = Vt + (size_t)bh * HEAD * T_SZ;

    __shared__ alignas(16) char SMEM[65536];
    char* Kbuf = SMEM + grp * 32768;
    char* Vbuf = Kbuf + 16384;

    const int srow = wl * 8 + (lane >> 3);
    const int sslot = (lane & 7) * 16;
    const int ssb = (sslot ^ ((srow & 7) << 4)) >> 1;
    const int kvbase = grp << 10;

    const int q0 = qt * 256 + wl * 32;
    bf16x8 qf[2][2];
    #pragma unroll
    for (int cc = 0; cc < 2; ++cc) {
        qf[cc][0] = *(const bf16x8*)(&Qp[(size_t)(q0 + cc * 16 + r15) * 64 + q4 * 8]);
        qf[cc][1] = *(const bf16x8*)(&Qp[(size_t)(q0 + cc * 16 + r15) * 64 + 32 + q4 * 8]);
    }

    const bf16x8 ones8 = {0x3F80, 0x3F80, 0x3F80, 0x3F80, 0x3F80, 0x3F80, 0x3F80, 0x3F80};

    f32x4 acc[2][4] = {};
    f32x4 acc_l[2] = {};

    #define STAGE(buf, kv0)                                                      \
        {                                                                        \
            gl2lds16(Kp + (size_t)(kvbase + (kv0) + srow) * 64 + ssb,            \
                     Kbuf + (buf) * 8192 + wl * 8 * 128);                        \
            gl2lds16(Vp + (size_t)srow * 2048 + kvbase + (kv0) + ssb,            \
                     Vbuf + (buf) * 8192 + wl * 8 * 128);                        \
        }

    STAGE(0, 0);
    int cur = 0;
    for (int it = 0; it < 16; ++it) {
        STAGE(cur ^ 1, ((it + 1) & 15) * 64);
        asm volatile("s_waitcnt vmcnt(2)" ::: "memory");
        RAW_BARRIER();

        const char* Ks = Kbuf + cur * 8192;
        const char* Vs = Vbuf + cur * 8192;

        bf16x8 kf[4][2];
        #pragma unroll
        for (int t4 = 0; t4 < 4; ++t4) {
            int row = t4 * 16 + r15;
            int sw = (row & 7) << 4;
            kf[t4][0] = *(const bf16x8*)(&Ks[row * 128 + ((q4 * 16) ^ sw)]);
            kf[t4][1] = *(const bf16x8*)(&Ks[row * 128 + ((64 + q4 * 16) ^ sw)]);
        }
        bf16x8 vf8[2][4];
        #pragma unroll
        for (int dt = 0; dt < 4; ++dt) {
            int row = dt * 16 + r15;
            int sw = (row & 7) << 4;
            #pragma unroll
            for (int t32 = 0; t32 < 2; ++t32)
                vf8[t32][dt] = *(const bf16x8*)(&Vs[row * 128 + ((t32 * 64 + q4 * 16) ^ sw)]);
        }

        f32x4 z[2][4];
        #pragma unroll
        for (int cc = 0; cc < 2; ++cc)
            #pragma unroll
            for (int t4 = 0; t4 < 4; ++t4) {
                f32x4 zz = {};
                zz = MFMA32(kf[t4][0], qf[cc][0], zz);
                zz = MFMA32(kf[t4][1], qf[cc][1], zz);
                z[cc][t4] = zz;
            }

        bf16x8 pb8[2][2];
        #pragma unroll
        for (int cc = 0; cc < 2; ++cc)
            #pragma unroll
            for (int t32 = 0; t32 < 2; ++t32)
                #pragma unroll
                for (int i = 0; i < 4; ++i) {
                    pb8[cc][t32][i]     = (short)f2bf_fast(exp2fast(z[cc][2 * t32][i]));
                    pb8[cc][t32][4 + i] = (short)f2bf_fast(exp2fast(z[cc][2 * t32 + 1][i]));
                }

        #pragma unroll
        for (int t32 = 0; t32 < 2; ++t32) {
            #pragma unroll
            for (int dt = 0; dt < 4; ++dt)
                #pragma unroll
                for (int cc = 0; cc < 2; ++cc)
                    acc[cc][dt] = MFMA32(vf8[t32][dt], pb8[cc][t32], acc[cc][dt]);
            #pragma unroll
            for (int cc = 0; cc < 2; ++cc)
                acc_l[cc] = MFMA32(ones8, pb8[cc][t32], acc_l[cc]);
        }

        RAW_BARRIER();
        cur ^= 1;
    }
    #undef STAGE

    asm volatile("s_waitcnt vmcnt(0)" ::: "memory");
    __syncthreads();

    float l0 = acc_l[0][0], l1 = acc_l[1][0];
    {
        float* MB = (float*)SMEM;
        #pragma unroll
        for (int rnd = 0; rnd < 2; ++rnd) {
            __syncthreads();
            if (grp == 1 && (wl >> 2) == rnd) {
                float* p = MB + (((wl & 3) * 64 + lane) * 34);
                #pragma unroll
                for (int cc = 0; cc < 2; ++cc)
                    #pragma unroll
                    for (int dt = 0; dt < 4; ++dt) {
                        *(float2*)(p + (cc * 4 + dt) * 4)     = make_float2(acc[cc][dt][0], acc[cc][dt][1]);
                        *(float2*)(p + (cc * 4 + dt) * 4 + 2) = make_float2(acc[cc][dt][2], acc[cc][dt][3]);
                    }
                *(float2*)(p + 32) = make_float2(l0, l1);
            }
            __syncthreads();
            if (grp == 0 && (wl >> 2) == rnd) {
                const float* p = MB + (((wl & 3) * 64 + lane) * 34);
                #pragma unroll
                for (int cc = 0; cc < 2; ++cc)
                    #pragma unroll
                    for (int dt = 0; dt < 4; ++dt)
                        #pragma unroll
                        for (int i = 0; i < 4; ++i)
                            acc[cc][dt][i] += p[(cc * 4 + dt) * 4 + i];
                l0 += p[32];
                l1 += p[33];
            }
        }
    }

    if (grp == 0) {
        const int b = bh >> 4, h = bh & 15;
        #pragma unroll
        for (int cc = 0; cc < 2; ++cc) {
            float inv = 1.0f / (cc ? l1 : l0);
            int q = q0 + cc * 16 + r15;
            #pragma unroll
            for (int dt = 0; dt < 4; ++dt) {
                ushort4 o;
                o.x = f2bf(acc[cc][dt][0] * inv);
                o.y = f2bf(acc[cc][dt][1] * inv);
                o.z = f2bf(acc[cc][dt][2] * inv);
                o.w = f2bf(acc[cc][dt][3] * inv);
                *(ushort4*)(&Ob[((size_t)(b * T_SZ + q)) * KD + h * HEAD + dt * 16 + q4 * 4]) = o;
            }
        }
    }
}

extern "C" void kernel_launch(void* const* d_in, const int* in_sizes, int n_in,
                              void* d_out, int out_size, void* d_ws, size_t ws_size,
                              hipStream_t stream) {
    const float* x  = (const float*)d_in[0];
    const float* Wq = (const float*)d_in[1];
    const float* Wk = (const float*)d_in[2];
    const float* Wv = (const float*)d_in[3];
    const float* Wo = (const float*)d_in[4];

    char* ws = (char*)d_ws;
    const size_t MB = 1024 * 1024;
    ushort* xb    = (ushort*)(ws + 0);
    ushort* Wqkvb = (ushort*)(ws + 8  * MB);
    ushort* Wob   = Wqkvb + 3 * (size_t)KD * KD;
    ushort* Qh    = (ushort*)(ws + 16 * MB);
    ushort* Kh    = (ushort*)(ws + 24 * MB);
    ushort* VhT   = (ushort*)(ws + 32 * MB);
    ushort* Ob    = (ushort*)(ws + 40 * MB);

    {
        int total4 = (M_TOT * KD) / 4 + KD * KD;
        cvt_all<<<total4 / 256, 256, 0, stream>>>(x, Wq, Wk, Wv, Wo, xb, Wqkvb);
    }

    gemm_qkv<<<dim3(16, 12), 512, 0, stream>>>(xb, Wqkvb, Qh);
    attn_fwd<<<dim3(32, 8), 1024, 0, stream>>>(Qh, Kh, VhT, Ob);
    gemm_o<<<dim3(32, 16), 512, 0, stream>>>(Ob, Wob, (float*)d_out);
}